// Round 1
// baseline (520.544 us; speedup 1.0000x reference)
//
#include <hip/hip_runtime.h>

// N=4096 nodes, H=8 heads, D=64, C=512. All fp32 in, fp32 out.
// Pipeline: convert->GEMM(qkv+skip)->flash attn w/ edge term->GraphNorm->L2.

typedef short s8v __attribute__((ext_vector_type(8)));       // 8 bf16 (A/B frag)
typedef unsigned short u16x8 __attribute__((ext_vector_type(8)));
typedef float f4 __attribute__((ext_vector_type(4)));        // C/D frag
typedef unsigned short u16;

__device__ __forceinline__ u16 f2bf(float f) {
    union { float f; unsigned u; } v; v.f = f;
    unsigned r = v.u + 0x7fffu + ((v.u >> 16) & 1u);
    return (u16)(r >> 16);
}
__device__ __forceinline__ float bf2f(u16 h) {
    union { unsigned u; float f; } v; v.u = ((unsigned)h) << 16;
    return v.f;
}

#define GLD16(g, l) __builtin_amdgcn_global_load_lds( \
    (const __attribute__((address_space(1))) void*)(g), \
    (__attribute__((address_space(3))) void*)(l), 16, 0, 0)

// ---------- zero the stats accumulator (ws is poisoned each launch) ----------
__global__ void k_zero(float* stats) { stats[threadIdx.x] = 0.f; }  // 1024 threads

// ---------- x fp32 -> bf16 ----------
__global__ __launch_bounds__(256) void k_convx(const float* __restrict__ x,
                                               u16* __restrict__ xb) {
    size_t i = ((size_t)blockIdx.x * 256 + threadIdx.x) * 8;
    float4 a = *(const float4*)(x + i);
    float4 b = *(const float4*)(x + i + 4);
    u16x8 o;
    o[0]=f2bf(a.x); o[1]=f2bf(a.y); o[2]=f2bf(a.z); o[3]=f2bf(a.w);
    o[4]=f2bf(b.x); o[5]=f2bf(b.y); o[6]=f2bf(b.z); o[7]=f2bf(b.w);
    *(u16x8*)(xb + i) = o;
}

// ---------- W concat transpose+convert: wb[n][k] = W_seg[k][n&511], bf16 ----------
__global__ __launch_bounds__(256) void k_transw(const float* __restrict__ Wq,
                                                const float* __restrict__ Wk,
                                                const float* __restrict__ Wv,
                                                const float* __restrict__ Ws,
                                                u16* __restrict__ wb) {
    __shared__ float tile[64][65];  // +1 pad breaks bank conflicts on transposed read
    int k0 = blockIdx.x * 64;
    int n0 = blockIdx.y * 64;
    const float* W = (n0 < 512) ? Wq : (n0 < 1024) ? Wk : (n0 < 1536) ? Wv : Ws;
    int col0 = n0 & 511;
    int t = threadIdx.x;
#pragma unroll
    for (int q = 0; q < 4; q++) {
        int idx = t + 256 * q;
        int row = idx >> 4, c4 = (idx & 15) * 4;
        float4 v = *(const float4*)&W[(size_t)(k0 + row) * 512 + col0 + c4];
        tile[row][c4 + 0] = v.x; tile[row][c4 + 1] = v.y;
        tile[row][c4 + 2] = v.z; tile[row][c4 + 3] = v.w;
    }
    __syncthreads();
#pragma unroll
    for (int q = 0; q < 2; q++) {
        int idx = t + 256 * q;
        int row = idx >> 3, c8 = (idx & 7) * 8;
        u16x8 o;
#pragma unroll
        for (int j = 0; j < 8; j++) o[j] = f2bf(tile[c8 + j][row]);
        *(u16x8*)&wb[(size_t)(n0 + row) * 4096 + k0 + c8] = o;
    }
}

// ---------- GEMM: qkvs[m][n] = bf16( sum_k xb[m][k]*wb[n][k] + bias[n] ) ----------
// 128x128 tile, BK=32, 4 waves each 64x64 (4x4 of 16x16x32 MFMA), global_load_lds.
__global__ __launch_bounds__(256) void k_gemm(const u16* __restrict__ xb,
                                              const u16* __restrict__ wb,
                                              const float* __restrict__ bq,
                                              const float* __restrict__ bk,
                                              const float* __restrict__ bv,
                                              const float* __restrict__ bs,
                                              u16* __restrict__ qkvs) {
    __shared__ __align__(16) u16 A_lds[128 * 32];
    __shared__ __align__(16) u16 B_lds[128 * 32];
    int tid = threadIdx.x;
    int w = tid >> 6, lane = tid & 63;
    int wr = w >> 1, wc = w & 1;
    int m0 = blockIdx.y * 128, n0 = blockIdx.x * 128;

    const f4 fz = {0.f, 0.f, 0.f, 0.f};
    f4 acc[4][4];
#pragma unroll
    for (int r = 0; r < 4; r++)
#pragma unroll
        for (int t = 0; t < 4; t++) acc[r][t] = fz;

    int srow = lane >> 2;           // 0..15 (16 rows per instr)
    int scol = (lane & 3) * 8;      // u16 offset within 64B row chunk
    const u16* gA0 = xb + (size_t)(m0 + 32 * w + srow) * 4096 + scol;
    const u16* gB0 = wb + (size_t)(n0 + 32 * w + srow) * 4096 + scol;

    for (int kt = 0; kt < 128; ++kt) {
        int k0 = kt * 32;
        GLD16(gA0 + k0,             &A_lds[(32 * w) * 32]);
        GLD16(gA0 + k0 + 16 * 4096, &A_lds[(32 * w + 16) * 32]);
        GLD16(gB0 + k0,             &B_lds[(32 * w) * 32]);
        GLD16(gB0 + k0 + 16 * 4096, &B_lds[(32 * w + 16) * 32]);
        __syncthreads();
        s8v a[4], b[4];
#pragma unroll
        for (int r = 0; r < 4; r++)
            a[r] = *(const s8v*)&A_lds[(wr * 64 + 16 * r + (lane & 15)) * 32 + (lane >> 4) * 8];
#pragma unroll
        for (int t = 0; t < 4; t++)
            b[t] = *(const s8v*)&B_lds[(wc * 64 + 16 * t + (lane & 15)) * 32 + (lane >> 4) * 8];
#pragma unroll
        for (int r = 0; r < 4; r++)
#pragma unroll
            for (int t = 0; t < 4; t++)
                acc[r][t] = __builtin_amdgcn_mfma_f32_16x16x32_bf16(a[r], b[t], acc[r][t], 0, 0, 0);
        __syncthreads();
    }

#pragma unroll
    for (int t = 0; t < 4; t++) {
        int n = n0 + wc * 64 + 16 * t + (lane & 15);
        int seg = n >> 9, o = n & 511;
        const float* bp = (seg == 0) ? bq : (seg == 1) ? bk : (seg == 2) ? bv : bs;
        float bias = bp[o];
#pragma unroll
        for (int r = 0; r < 4; r++) {
            int mbase = m0 + wr * 64 + 16 * r + ((lane >> 4) << 2);
#pragma unroll
            for (int q2 = 0; q2 < 4; q2++)
                qkvs[(size_t)(mbase + q2) * 2048 + n] = f2bf(acc[r][t][q2] + bias);
        }
    }
}

// ---------- fused attention + edge term + skip -> out_pre (fp32) ----------
// block = (i-tile of 64 rows, head h); 4 waves, wave w owns rows 16w..16w+15.
// j-loop over 64-wide tiles: QK^T MFMA -> scores(+edge) -> online softmax ->
// P through LDS -> PV MFMA. s = sum_j alpha*x[j,i] accumulated alongside.
__global__ __launch_bounds__(256) void k_attn(const u16* __restrict__ qkvs,
                                              const float* __restrict__ x,
                                              const float* __restrict__ we,
                                              float* __restrict__ out_pre) {
    __shared__ __align__(16) u16 K_lds[64 * 80];   // [j][d], stride 80
    __shared__ __align__(16) u16 Vt_lds[64 * 80];  // [d][j], stride 80
    __shared__ __align__(16) u16 P_lds[64 * 80];   // [i][j], stride 80 (also Q staging)
    __shared__ __align__(16) float X_lds[64 * 68]; // [j][i], stride 68 (fp32 edge attrs)
    __shared__ float qe8[64];

    int tid = threadIdx.x;
    int w = tid >> 6, lane = tid & 63;
    int i0 = blockIdx.x * 64;
    int h = blockIdx.y;
    int hc = h * 64;

    // stage Q (rows i0..i0+63, cols hc..hc+63) into P_lds
#pragma unroll
    for (int q = 0; q < 2; q++) {
        int idx = tid + 256 * q;
        int row = idx >> 3, c8 = (idx & 7) * 8;
        *(s8v*)&P_lds[row * 80 + c8] =
            *(const s8v*)&qkvs[(size_t)(i0 + row) * 2048 + hc + c8];
    }
    __syncthreads();

    s8v qf[2];
#pragma unroll
    for (int c = 0; c < 2; c++)
        qf[c] = *(const s8v*)&P_lds[(16 * w + (lane & 15)) * 80 + 32 * c + (lane >> 4) * 8];

    if (tid < 64) {  // qe8[i] = (q[i]·we_h) / 8
        float s = 0.f;
        for (int d = 0; d < 64; d++) s += bf2f(P_lds[tid * 80 + d]) * we[hc + d];
        qe8[tid] = s * 0.125f;
    }
    __syncthreads();

    const f4 fz = {0.f, 0.f, 0.f, 0.f};
    float m_r[4], l_r[4], sa_r[4], qe_r[4];
    f4 o_acc[4];
#pragma unroll
    for (int r = 0; r < 4; r++) {
        m_r[r] = -3.0e38f; l_r[r] = 0.f; sa_r[r] = 0.f;
        qe_r[r] = qe8[16 * w + ((lane >> 4) << 2) + r];
    }
#pragma unroll
    for (int t = 0; t < 4; t++) o_acc[t] = fz;

    for (int jt64 = 0; jt64 < 64; ++jt64) {
        int j0 = jt64 * 64;
        // stage K
#pragma unroll
        for (int q = 0; q < 2; q++) {
            int idx = tid + 256 * q;
            int row = idx >> 3, c8 = (idx & 7) * 8;
            *(s8v*)&K_lds[row * 80 + c8] =
                *(const s8v*)&qkvs[(size_t)(j0 + row) * 2048 + 512 + hc + c8];
        }
        // stage V transposed
#pragma unroll
        for (int q = 0; q < 2; q++) {
            int idx = tid + 256 * q;
            int row = idx >> 3, c8 = (idx & 7) * 8;
            s8v v = *(const s8v*)&qkvs[(size_t)(j0 + row) * 2048 + 1024 + hc + c8];
#pragma unroll
            for (int j = 0; j < 8; j++) Vt_lds[(c8 + j) * 80 + row] = (u16)v[j];
        }
        // stage X tile: X_lds[j][i] = x[j0+j][i0+i]  (fp32 edge attrs)
#pragma unroll
        for (int q = 0; q < 4; q++) {
            int idx = tid + 256 * q;
            int row = idx >> 4, c4 = (idx & 15) * 4;
            *(float4*)&X_lds[row * 68 + c4] =
                *(const float4*)&x[(size_t)(j0 + row) * 4096 + i0 + c4];
        }
        __syncthreads();

        // QK^T + scale + edge term
        f4 s_t[4];
        float xv[4][4];
#pragma unroll
        for (int jt = 0; jt < 4; jt++) {
            s8v b0 = *(const s8v*)&K_lds[((lane & 15) + 16 * jt) * 80 + (lane >> 4) * 8];
            s8v b1 = *(const s8v*)&K_lds[((lane & 15) + 16 * jt) * 80 + 32 + (lane >> 4) * 8];
            f4 acc = fz;
            acc = __builtin_amdgcn_mfma_f32_16x16x32_bf16(qf[0], b0, acc, 0, 0, 0);
            acc = __builtin_amdgcn_mfma_f32_16x16x32_bf16(qf[1], b1, acc, 0, 0, 0);
            int jl = (lane & 15) + 16 * jt;
#pragma unroll
            for (int r = 0; r < 4; r++) {
                int il = 16 * w + ((lane >> 4) << 2) + r;
                float xx = X_lds[jl * 68 + il];
                xv[jt][r] = xx;
                s_t[jt][r] = acc[r] * 0.125f + xx * qe_r[r];
            }
        }

        // online softmax update (rows live in C-layout: 16 lanes/row, shfl over low 4 bits)
#pragma unroll
        for (int r = 0; r < 4; r++) {
            float mx = fmaxf(fmaxf(s_t[0][r], s_t[1][r]), fmaxf(s_t[2][r], s_t[3][r]));
            mx = fmaxf(mx, __shfl_xor(mx, 1));
            mx = fmaxf(mx, __shfl_xor(mx, 2));
            mx = fmaxf(mx, __shfl_xor(mx, 4));
            mx = fmaxf(mx, __shfl_xor(mx, 8));
            float mnew = fmaxf(m_r[r], mx);
            float alpha = __expf(m_r[r] - mnew);
            m_r[r] = mnew;
            float rs = 0.f, se = 0.f;
#pragma unroll
            for (int jt = 0; jt < 4; jt++) {
                float p = __expf(s_t[jt][r] - mnew);
                s_t[jt][r] = p;
                rs += p;
                se += p * xv[jt][r];
            }
            rs += __shfl_xor(rs, 1); se += __shfl_xor(se, 1);
            rs += __shfl_xor(rs, 2); se += __shfl_xor(se, 2);
            rs += __shfl_xor(rs, 4); se += __shfl_xor(se, 4);
            rs += __shfl_xor(rs, 8); se += __shfl_xor(se, 8);
            l_r[r] = l_r[r] * alpha + rs;
            sa_r[r] = sa_r[r] * alpha + se;
#pragma unroll
            for (int t = 0; t < 4; t++) o_acc[t][r] *= alpha;
        }

        // P (C-layout) -> LDS -> A-layout for PV. Same-wave rows only: no barrier needed.
#pragma unroll
        for (int jt = 0; jt < 4; jt++)
#pragma unroll
            for (int r = 0; r < 4; r++)
                P_lds[(16 * w + ((lane >> 4) << 2) + r) * 80 + (lane & 15) + 16 * jt] =
                    f2bf(s_t[jt][r]);

        s8v a0 = *(const s8v*)&P_lds[(16 * w + (lane & 15)) * 80 + (lane >> 4) * 8];
        s8v a1 = *(const s8v*)&P_lds[(16 * w + (lane & 15)) * 80 + 32 + (lane >> 4) * 8];
#pragma unroll
        for (int t = 0; t < 4; t++) {
            s8v b0 = *(const s8v*)&Vt_lds[((lane & 15) + 16 * t) * 80 + (lane >> 4) * 8];
            s8v b1 = *(const s8v*)&Vt_lds[((lane & 15) + 16 * t) * 80 + 32 + (lane >> 4) * 8];
            o_acc[t] = __builtin_amdgcn_mfma_f32_16x16x32_bf16(a0, b0, o_acc[t], 0, 0, 0);
            o_acc[t] = __builtin_amdgcn_mfma_f32_16x16x32_bf16(a1, b1, o_acc[t], 0, 0, 0);
        }
        __syncthreads();
    }

    // epilogue: out_pre = O/l + (s/l)*we_h + skip
    float wec[4];
#pragma unroll
    for (int t = 0; t < 4; t++) wec[t] = we[hc + (lane & 15) + 16 * t];
#pragma unroll
    for (int r = 0; r < 4; r++) {
        float invl = 1.f / l_r[r];
        float sv = sa_r[r] * invl;
        int i = i0 + 16 * w + ((lane >> 4) << 2) + r;
#pragma unroll
        for (int t = 0; t < 4; t++) {
            int cc = hc + (lane & 15) + 16 * t;
            float skip = bf2f(qkvs[(size_t)i * 2048 + 1536 + cc]);
            out_pre[(size_t)i * 512 + cc] = o_acc[t][r] * invl + sv * wec[t] + skip;
        }
    }
}

// ---------- per-channel sum / sumsq ----------
__global__ __launch_bounds__(512) void k_stats(const float* __restrict__ out_pre,
                                               float* __restrict__ stats) {
    int c = threadIdx.x;
    int r0 = blockIdx.x * 64;
    float s = 0.f, s2 = 0.f;
    for (int i = 0; i < 64; i++) {
        float v = out_pre[(size_t)(r0 + i) * 512 + c];
        s += v; s2 += v * v;
    }
    atomicAdd(&stats[c], s);
    atomicAdd(&stats[512 + c], s2);
}

// ---------- GraphNorm + per-row L2 normalize ----------
__global__ __launch_bounds__(512) void k_final(const float* __restrict__ out_pre,
                                               const float* __restrict__ stats,
                                               const float* __restrict__ gn_w,
                                               const float* __restrict__ gn_b,
                                               const float* __restrict__ gn_ms,
                                               float* __restrict__ out) {
    __shared__ float red[8];
    int c = threadIdx.x;
    int i = blockIdx.x;
    float mean = stats[c] * (1.f / 4096.f);
    float ex2 = stats[512 + c] * (1.f / 4096.f);
    float g = gn_ms[c];
    // var = E[(v - g*mean)^2] = E[v^2] - (2g - g^2)*mean^2   (since E[v]=mean)
    float var = ex2 - (2.f * g - g * g) * mean * mean;
    float y = gn_w[c] * (out_pre[(size_t)i * 512 + c] - g * mean) * rsqrtf(var + 1e-5f) + gn_b[c];
    float q = y * y;
    q += __shfl_xor(q, 1);  q += __shfl_xor(q, 2);  q += __shfl_xor(q, 4);
    q += __shfl_xor(q, 8);  q += __shfl_xor(q, 16); q += __shfl_xor(q, 32);
    if ((c & 63) == 0) red[c >> 6] = q;
    __syncthreads();
    float tot = 0.f;
#pragma unroll
    for (int k = 0; k < 8; k++) tot += red[k];
    out[(size_t)i * 512 + c] = y * rsqrtf(tot);
}

extern "C" void kernel_launch(void* const* d_in, const int* in_sizes, int n_in,
                              void* d_out, int out_size, void* d_ws, size_t ws_size,
                              hipStream_t stream) {
    (void)in_sizes; (void)n_in; (void)out_size; (void)ws_size;
    const float* x    = (const float*)d_in[0];
    const float* Wq   = (const float*)d_in[1];
    const float* bq   = (const float*)d_in[2];
    const float* Wk   = (const float*)d_in[3];
    const float* bk   = (const float*)d_in[4];
    const float* Wv   = (const float*)d_in[5];
    const float* bv   = (const float*)d_in[6];
    const float* we   = (const float*)d_in[7];
    const float* Ws   = (const float*)d_in[8];
    const float* bs   = (const float*)d_in[9];
    const float* gnw  = (const float*)d_in[10];
    const float* gnb  = (const float*)d_in[11];
    const float* gnms = (const float*)d_in[12];
    float* out = (float*)d_out;

    char* ws = (char*)d_ws;
    u16* xb        = (u16*)(ws);                           // 32 MB  bf16 x
    u16* wb        = (u16*)(ws + (size_t)33554432);        // 16 MB  bf16 W^T concat [2048][4096]
    u16* qkvs      = (u16*)(ws + (size_t)50331648);        // 16 MB  bf16 [4096][q|k|v|skip]
    float* out_pre = (float*)(ws + (size_t)67108864);      // 8 MB   fp32 pre-norm
    float* stats   = (float*)(ws + (size_t)75497472);      // 4 KB   col sums/sumsq

    k_zero<<<1, 1024, 0, stream>>>(stats);
    k_convx<<<8192, 256, 0, stream>>>(x, xb);
    k_transw<<<dim3(64, 32), 256, 0, stream>>>(Wq, Wk, Wv, Ws, wb);
    k_gemm<<<dim3(16, 32), 256, 0, stream>>>(xb, wb, bq, bk, bv, bs, qkvs);
    k_attn<<<dim3(64, 8), 256, 0, stream>>>(qkvs, x, we, out_pre);
    k_stats<<<64, 512, 0, stream>>>(out_pre, stats);
    k_final<<<4096, 512, 0, stream>>>(out_pre, stats, gnw, gnb, gnms, out);
}

// Round 3
// 344.534 us; speedup vs baseline: 1.5109x; 1.5109x over previous
//
#include <hip/hip_runtime.h>

// N=4096 nodes, H=8 heads, D=64, C=512. All fp32 in, fp32 out.
// Pipeline: convert -> GEMM(qkv+skip) -> transpose V -> split-j max-free flash
// attn w/ edge term -> combine(+skip+stats) -> GraphNorm+L2.

typedef short s8v __attribute__((ext_vector_type(8)));       // 8 bf16 (A/B frag)
typedef unsigned short u16x8 __attribute__((ext_vector_type(8)));
typedef unsigned short u16x4 __attribute__((ext_vector_type(4)));
typedef float f4 __attribute__((ext_vector_type(4)));        // C/D frag
typedef unsigned short u16;

__device__ __forceinline__ u16 f2bf(float f) {
    union { float f; unsigned u; } v; v.f = f;
    unsigned r = v.u + 0x7fffu + ((v.u >> 16) & 1u);
    return (u16)(r >> 16);
}
__device__ __forceinline__ float bf2f(u16 h) {
    union { unsigned u; float f; } v; v.u = ((unsigned)h) << 16;
    return v.f;
}

#define GLD16(g, l) __builtin_amdgcn_global_load_lds( \
    (const __attribute__((address_space(1))) void*)(g), \
    (__attribute__((address_space(3))) void*)(l), 16, 0, 0)

// ---------- zero the stats accumulator (ws is poisoned each launch) ----------
__global__ void k_zero(float* stats) { stats[threadIdx.x] = 0.f; }  // 1024 threads

// ---------- x fp32 -> bf16 ----------
__global__ __launch_bounds__(256) void k_convx(const float* __restrict__ x,
                                               u16* __restrict__ xb) {
    size_t i = ((size_t)blockIdx.x * 256 + threadIdx.x) * 8;
    float4 a = *(const float4*)(x + i);
    float4 b = *(const float4*)(x + i + 4);
    u16x8 o;
    o[0]=f2bf(a.x); o[1]=f2bf(a.y); o[2]=f2bf(a.z); o[3]=f2bf(a.w);
    o[4]=f2bf(b.x); o[5]=f2bf(b.y); o[6]=f2bf(b.z); o[7]=f2bf(b.w);
    *(u16x8*)(xb + i) = o;
}

// ---------- W concat transpose+convert: wb[n][k] = W_seg[k][n&511], bf16 ----------
__global__ __launch_bounds__(256) void k_transw(const float* __restrict__ Wq,
                                                const float* __restrict__ Wk,
                                                const float* __restrict__ Wv,
                                                const float* __restrict__ Ws,
                                                u16* __restrict__ wb) {
    __shared__ float tile[64][65];
    int k0 = blockIdx.x * 64;
    int n0 = blockIdx.y * 64;
    const float* W = (n0 < 512) ? Wq : (n0 < 1024) ? Wk : (n0 < 1536) ? Wv : Ws;
    int col0 = n0 & 511;
    int t = threadIdx.x;
#pragma unroll
    for (int q = 0; q < 4; q++) {
        int idx = t + 256 * q;
        int row = idx >> 4, c4 = (idx & 15) * 4;
        float4 v = *(const float4*)&W[(size_t)(k0 + row) * 512 + col0 + c4];
        tile[row][c4 + 0] = v.x; tile[row][c4 + 1] = v.y;
        tile[row][c4 + 2] = v.z; tile[row][c4 + 3] = v.w;
    }
    __syncthreads();
#pragma unroll
    for (int q = 0; q < 2; q++) {
        int idx = t + 256 * q;
        int row = idx >> 3, c8 = (idx & 7) * 8;
        u16x8 o;
#pragma unroll
        for (int j = 0; j < 8; j++) o[j] = f2bf(tile[c8 + j][row]);
        *(u16x8*)&wb[(size_t)(n0 + row) * 4096 + k0 + c8] = o;
    }
}

// ---------- GEMM: qkvs[m][n] = bf16( sum_k xb[m][k]*wb[n][k] + bias[n] ) ----------
__global__ __launch_bounds__(256) void k_gemm(const u16* __restrict__ xb,
                                              const u16* __restrict__ wb,
                                              const float* __restrict__ bq,
                                              const float* __restrict__ bk,
                                              const float* __restrict__ bv,
                                              const float* __restrict__ bs,
                                              u16* __restrict__ qkvs) {
    __shared__ __align__(16) u16 A_lds[128 * 32];
    __shared__ __align__(16) u16 B_lds[128 * 32];
    int tid = threadIdx.x;
    int w = tid >> 6, lane = tid & 63;
    int wr = w >> 1, wc = w & 1;
    int m0 = blockIdx.y * 128, n0 = blockIdx.x * 128;

    const f4 fz = {0.f, 0.f, 0.f, 0.f};
    f4 acc[4][4];
#pragma unroll
    for (int r = 0; r < 4; r++)
#pragma unroll
        for (int t = 0; t < 4; t++) acc[r][t] = fz;

    int srow = lane >> 2;
    int scol = (lane & 3) * 8;
    const u16* gA0 = xb + (size_t)(m0 + 32 * w + srow) * 4096 + scol;
    const u16* gB0 = wb + (size_t)(n0 + 32 * w + srow) * 4096 + scol;

    for (int kt = 0; kt < 128; ++kt) {
        int k0 = kt * 32;
        GLD16(gA0 + k0,             &A_lds[(32 * w) * 32]);
        GLD16(gA0 + k0 + 16 * 4096, &A_lds[(32 * w + 16) * 32]);
        GLD16(gB0 + k0,             &B_lds[(32 * w) * 32]);
        GLD16(gB0 + k0 + 16 * 4096, &B_lds[(32 * w + 16) * 32]);
        __syncthreads();
        s8v a[4], b[4];
#pragma unroll
        for (int r = 0; r < 4; r++)
            a[r] = *(const s8v*)&A_lds[(wr * 64 + 16 * r + (lane & 15)) * 32 + (lane >> 4) * 8];
#pragma unroll
        for (int t = 0; t < 4; t++)
            b[t] = *(const s8v*)&B_lds[(wc * 64 + 16 * t + (lane & 15)) * 32 + (lane >> 4) * 8];
#pragma unroll
        for (int r = 0; r < 4; r++)
#pragma unroll
            for (int t = 0; t < 4; t++)
                acc[r][t] = __builtin_amdgcn_mfma_f32_16x16x32_bf16(a[r], b[t], acc[r][t], 0, 0, 0);
        __syncthreads();
    }

#pragma unroll
    for (int t = 0; t < 4; t++) {
        int n = n0 + wc * 64 + 16 * t + (lane & 15);
        int seg = n >> 9, o = n & 511;
        const float* bp = (seg == 0) ? bq : (seg == 1) ? bk : (seg == 2) ? bv : bs;
        float bias = bp[o];
#pragma unroll
        for (int r = 0; r < 4; r++) {
            int mbase = m0 + wr * 64 + 16 * r + ((lane >> 4) << 2);
#pragma unroll
            for (int q2 = 0; q2 < 4; q2++)
                qkvs[(size_t)(mbase + q2) * 2048 + n] = f2bf(acc[r][t][q2] + bias);
        }
    }
}

// ---------- global V transpose: vt[d][j] = qkvs[j][1024+d], bf16 ----------
// u32 LDS tile, odd stride 65 -> conflict-free scalar transpose.
__global__ __launch_bounds__(256) void k_transv(const u16* __restrict__ qkvs,
                                                u16* __restrict__ vt) {
    __shared__ unsigned tile[64 * 65];
    int j0 = blockIdx.x * 64, d0 = blockIdx.y * 64;
    int t = threadIdx.x;
#pragma unroll
    for (int q = 0; q < 2; q++) {
        int idx = t + 256 * q;
        int row = idx >> 3, c8 = (idx & 7) * 8;
        s8v v = *(const s8v*)&qkvs[(size_t)(j0 + row) * 2048 + 1024 + d0 + c8];
#pragma unroll
        for (int j = 0; j < 8; j++) tile[row * 65 + c8 + j] = (unsigned)(u16)v[j];
    }
    __syncthreads();
#pragma unroll
    for (int q = 0; q < 2; q++) {
        int idx = t + 256 * q;
        int row = idx >> 3, c8 = (idx & 7) * 8;
        u16x8 o;
#pragma unroll
        for (int j = 0; j < 8; j++) o[j] = (u16)tile[(c8 + j) * 65 + row];
        *(u16x8*)&vt[(size_t)(d0 + row) * 4096 + j0 + c8] = o;
    }
}

// ---------- split-j max-free attention ----------
// block = (i-tile 64, head h, split sp); 4 waves, wave w owns rows 16w..16w+15.
// K/V'/Q staged via GLD16 into unpadded 64x64 tiles with XOR chunk swizzle:
//   element (row, col) stored at chunk (col>>3)^(row&7)  -> bank-even b128 reads.
// p = exp(min(s,80)) with NO running max (scores are O(15), fp32 exp is safe);
// partials o, l, sa are pure sums -> j-split combine is trivial addition.
__global__ __launch_bounds__(256, 4) void k_attn(const u16* __restrict__ qkvs,
                                                 const u16* __restrict__ xb,
                                                 const u16* __restrict__ vt,
                                                 const float* __restrict__ we,
                                                 float* __restrict__ o_part,
                                                 float* __restrict__ lsa_part) {
    __shared__ __align__(16) u16 K_lds[64 * 64];  // swizzled (also Q staging)
    __shared__ __align__(16) u16 V_lds[64 * 64];  // swizzled, rows=d cols=j
    __shared__ __align__(16) u16 P_lds[64 * 72];  // padded, plain layout
    __shared__ __align__(16) u16 X_lds[64 * 72];  // padded bf16 x tile [j][i]
    __shared__ float qe8[64];

    int tid = threadIdx.x;
    int w = tid >> 6, lane = tid & 63;
    int L = lane & 15, q = lane >> 4;
    int i0 = blockIdx.x * 64;
    int h = blockIdx.y, hc = h * 64;
    int sp = blockIdx.z;

    int r8 = lane >> 3;                 // GLD16 source row within 8-row group
    int csw = ((lane & 7) ^ r8) * 8;    // XOR-swizzled source chunk (u16 units)

    // ---- stage Q into K_lds (GLD16, swizzled) ----
    {
        const u16* g0 = qkvs + (size_t)i0 * 2048 + hc;
#pragma unroll
        for (int ih = 0; ih < 2; ih++) {
            int rb = 16 * w + 8 * ih;
            GLD16(g0 + (size_t)(rb + r8) * 2048 + csw, &K_lds[rb * 64]);
        }
    }
    __syncthreads();

    s8v qf[2];
#pragma unroll
    for (int c = 0; c < 2; c++) {
        int row = 16 * w + L;
        qf[c] = *(const s8v*)&K_lds[row * 64 + (((4 * c + q) ^ (row & 7)) * 8)];
    }
    if (tid < 64) {  // qe8[i] = (q_i . we_h) / 8
        float s = 0.f;
        int r7 = tid & 7;
#pragma unroll
        for (int d = 0; d < 64; d++)
            s += bf2f(K_lds[tid * 64 + ((d >> 3) ^ r7) * 8 + (d & 7)]) * we[hc + d];
        qe8[tid] = s * 0.125f;
    }
    __syncthreads();

    float qe_r[4];
#pragma unroll
    for (int r = 0; r < 4; r++) qe_r[r] = qe8[16 * w + 4 * q + r];

    const f4 fz = {0.f, 0.f, 0.f, 0.f};
    f4 o_acc[4];
    float l_p[4], sa_p[4];
#pragma unroll
    for (int r = 0; r < 4; r++) { l_p[r] = 0.f; sa_p[r] = 0.f; }
#pragma unroll
    for (int t = 0; t < 4; t++) o_acc[t] = fz;

    for (int jt64 = 0; jt64 < 32; ++jt64) {
        int j0 = sp * 2048 + jt64 * 64;
        // stage K (GLD16)
        {
            const u16* g0 = qkvs + (size_t)j0 * 2048 + 512 + hc;
#pragma unroll
            for (int ih = 0; ih < 2; ih++) {
                int rb = 16 * w + 8 * ih;
                GLD16(g0 + (size_t)(rb + r8) * 2048 + csw, &K_lds[rb * 64]);
            }
        }
        // stage V^T (GLD16): rows are d, cols j
        {
            const u16* g0 = vt + (size_t)hc * 4096 + j0;
#pragma unroll
            for (int ih = 0; ih < 2; ih++) {
                int rb = 16 * w + 8 * ih;
                GLD16(g0 + (size_t)(rb + r8) * 4096 + csw, &V_lds[rb * 64]);
            }
        }
        // stage X tile bf16: X_lds[j][i] (padded 72, plain)
#pragma unroll
        for (int qq = 0; qq < 2; qq++) {
            int idx = tid + 256 * qq;
            int row = idx >> 3, c8 = (idx & 7) * 8;
            *(s8v*)&X_lds[row * 72 + c8] =
                *(const s8v*)&xb[(size_t)(j0 + row) * 4096 + i0 + c8];
        }
        __syncthreads();

#pragma unroll
        for (int jt = 0; jt < 4; jt++) {
            int n = L + 16 * jt;
            int n7 = n & 7;
            s8v b0 = *(const s8v*)&K_lds[n * 64 + ((q ^ n7) * 8)];
            s8v b1 = *(const s8v*)&K_lds[n * 64 + (((4 + q) ^ n7) * 8)];
            f4 acc = fz;
            acc = __builtin_amdgcn_mfma_f32_16x16x32_bf16(qf[0], b0, acc, 0, 0, 0);
            acc = __builtin_amdgcn_mfma_f32_16x16x32_bf16(qf[1], b1, acc, 0, 0, 0);
            u16x4 xv4 = *(const u16x4*)&X_lds[n * 72 + 16 * w + 4 * q];
#pragma unroll
            for (int r = 0; r < 4; r++) {
                float xx = bf2f(xv4[r]);
                float s = fminf(acc[r] * 0.125f + xx * qe_r[r], 80.f);
                float p = __expf(s);
                l_p[r] += p;
                sa_p[r] += p * xx;
                P_lds[(16 * w + 4 * q + r) * 72 + n] = f2bf(p);
            }
        }

        // PV (wave-local P round-trip; same-wave rows only)
        {
            int row = 16 * w + L;
            s8v a0 = *(const s8v*)&P_lds[row * 72 + q * 8];
            s8v a1 = *(const s8v*)&P_lds[row * 72 + 32 + q * 8];
#pragma unroll
            for (int t = 0; t < 4; t++) {
                int n = L + 16 * t;
                int n7 = n & 7;
                s8v b0 = *(const s8v*)&V_lds[n * 64 + ((q ^ n7) * 8)];
                s8v b1 = *(const s8v*)&V_lds[n * 64 + (((4 + q) ^ n7) * 8)];
                o_acc[t] = __builtin_amdgcn_mfma_f32_16x16x32_bf16(a0, b0, o_acc[t], 0, 0, 0);
                o_acc[t] = __builtin_amdgcn_mfma_f32_16x16x32_bf16(a1, b1, o_acc[t], 0, 0, 0);
            }
        }
        __syncthreads();
    }

    // epilogue: write raw partials (division happens in k_comb after summing l)
#pragma unroll
    for (int r = 0; r < 4; r++) {
        float l = l_p[r], sa = sa_p[r];
        l += __shfl_xor(l, 1);  sa += __shfl_xor(sa, 1);
        l += __shfl_xor(l, 2);  sa += __shfl_xor(sa, 2);
        l += __shfl_xor(l, 4);  sa += __shfl_xor(sa, 4);
        l += __shfl_xor(l, 8);  sa += __shfl_xor(sa, 8);
        int i = i0 + 16 * w + 4 * q + r;
#pragma unroll
        for (int t = 0; t < 4; t++)
            o_part[((size_t)sp * 4096 + i) * 512 + hc + L + 16 * t] = o_acc[t][r];
        if (L == 0) {
            size_t bi = (((size_t)sp * 4096 + i) * 8 + h) * 2;
            lsa_part[bi] = l;
            lsa_part[bi + 1] = sa;
        }
    }
}

// ---------- combine splits + skip + out_pre + column stats ----------
__global__ __launch_bounds__(512) void k_comb(const float* __restrict__ o_part,
                                              const float* __restrict__ lsa,
                                              const u16* __restrict__ qkvs,
                                              const float* __restrict__ we,
                                              float* __restrict__ out_pre,
                                              float* __restrict__ stats) {
    int c = threadIdx.x;
    int r0 = blockIdx.x * 64;
    int h = c >> 6;
    float wec = we[c];
    float s = 0.f, s2 = 0.f;
    for (int ii = 0; ii < 64; ii++) {
        int i = r0 + ii;
        size_t b0 = ((size_t)i * 8 + h) * 2;
        size_t b1 = (((size_t)4096 + i) * 8 + h) * 2;
        float l = lsa[b0] + lsa[b1];
        float sa = lsa[b0 + 1] + lsa[b1 + 1];
        float o = o_part[(size_t)i * 512 + c] + o_part[((size_t)4096 + i) * 512 + c];
        float inv = 1.f / l;
        float v = (o + sa * wec) * inv + bf2f(qkvs[(size_t)i * 2048 + 1536 + c]);
        out_pre[(size_t)i * 512 + c] = v;
        s += v; s2 += v * v;
    }
    atomicAdd(&stats[c], s);
    atomicAdd(&stats[512 + c], s2);
}

// ---------- GraphNorm + per-row L2 normalize ----------
__global__ __launch_bounds__(512) void k_final(const float* __restrict__ out_pre,
                                               const float* __restrict__ stats,
                                               const float* __restrict__ gn_w,
                                               const float* __restrict__ gn_b,
                                               const float* __restrict__ gn_ms,
                                               float* __restrict__ out) {
    __shared__ float red[8];
    int c = threadIdx.x;
    int i = blockIdx.x;
    float mean = stats[c] * (1.f / 4096.f);
    float ex2 = stats[512 + c] * (1.f / 4096.f);
    float g = gn_ms[c];
    float var = ex2 - (2.f * g - g * g) * mean * mean;
    float y = gn_w[c] * (out_pre[(size_t)i * 512 + c] - g * mean) * rsqrtf(var + 1e-5f) + gn_b[c];
    float qv = y * y;
    qv += __shfl_xor(qv, 1);  qv += __shfl_xor(qv, 2);  qv += __shfl_xor(qv, 4);
    qv += __shfl_xor(qv, 8);  qv += __shfl_xor(qv, 16); qv += __shfl_xor(qv, 32);
    if ((c & 63) == 0) red[c >> 6] = qv;
    __syncthreads();
    float tot = 0.f;
#pragma unroll
    for (int k = 0; k < 8; k++) tot += red[k];
    out[(size_t)i * 512 + c] = y * rsqrtf(tot);
}

extern "C" void kernel_launch(void* const* d_in, const int* in_sizes, int n_in,
                              void* d_out, int out_size, void* d_ws, size_t ws_size,
                              hipStream_t stream) {
    (void)in_sizes; (void)n_in; (void)out_size; (void)ws_size;
    const float* x    = (const float*)d_in[0];
    const float* Wq   = (const float*)d_in[1];
    const float* bq   = (const float*)d_in[2];
    const float* Wk   = (const float*)d_in[3];
    const float* bk   = (const float*)d_in[4];
    const float* Wv   = (const float*)d_in[5];
    const float* bv   = (const float*)d_in[6];
    const float* we   = (const float*)d_in[7];
    const float* Ws   = (const float*)d_in[8];
    const float* bs   = (const float*)d_in[9];
    const float* gnw  = (const float*)d_in[10];
    const float* gnb  = (const float*)d_in[11];
    const float* gnms = (const float*)d_in[12];
    float* out = (float*)d_out;

    char* ws = (char*)d_ws;
    // Region reuse (all launches sequential on `stream`):
    //   [0,32M):   xb (convx..attn) then out_pre overlays (comb..final)
    //   [32M,48M): wb (transw..gemm) then o_part overlays (attn..comb)
    //   [48M,64M): qkvs (gemm..comb)
    //   [64M,68M): vt
    //   [68M,+512K): lsa_part ; stats after it
    u16* xb        = (u16*)(ws);
    float* out_pre = (float*)(ws);
    u16* wb        = (u16*)(ws + (size_t)33554432);
    float* o_part  = (float*)(ws + (size_t)33554432);
    u16* qkvs      = (u16*)(ws + (size_t)50331648);
    u16* vt        = (u16*)(ws + (size_t)67108864);
    float* lsa     = (float*)(ws + (size_t)71303168);
    float* stats   = (float*)(ws + (size_t)71303168 + 524288);

    k_zero<<<1, 1024, 0, stream>>>(stats);
    k_convx<<<8192, 256, 0, stream>>>(x, xb);
    k_transw<<<dim3(64, 32), 256, 0, stream>>>(Wq, Wk, Wv, Ws, wb);
    k_gemm<<<dim3(16, 32), 256, 0, stream>>>(xb, wb, bq, bk, bv, bs, qkvs);
    k_transv<<<dim3(64, 8), 256, 0, stream>>>(qkvs, vt);
    k_attn<<<dim3(64, 8, 2), 256, 0, stream>>>(qkvs, xb, vt, we, o_part, lsa);
    k_comb<<<64, 512, 0, stream>>>(o_part, lsa, qkvs, we, out_pre, stats);
    k_final<<<4096, 512, 0, stream>>>(out_pre, stats, gnw, gnb, gnms, out);
}

// Round 4
// 337.300 us; speedup vs baseline: 1.5433x; 1.0214x over previous
//
#include <hip/hip_runtime.h>

// N=4096 nodes, H=8 heads, D=64, C=512. All fp32 in, fp32 out.
// Pipeline: convert(+stat zero) -> GEMM(qkv+skip, Q pre-scaled by 0.125*log2e,
// V also written transposed) -> split-j max-free flash attn (exp2 path) ->
// combine(+skip+stats) -> GraphNorm+L2.

typedef short s8v __attribute__((ext_vector_type(8)));       // 8 bf16 (A/B frag)
typedef unsigned short u16x8 __attribute__((ext_vector_type(8)));
typedef unsigned short u16x4 __attribute__((ext_vector_type(4)));
typedef float f4 __attribute__((ext_vector_type(4)));        // C/D frag
typedef unsigned short u16;

__device__ __forceinline__ u16 f2bf(float f) {               // RNE (cold paths)
    union { float f; unsigned u; } v; v.f = f;
    unsigned r = v.u + 0x7fffu + ((v.u >> 16) & 1u);
    return (u16)(r >> 16);
}
__device__ __forceinline__ u16 f2bf_hu(float f) {            // round-half-up, 2 ops (P>=0)
    union { float f; unsigned u; } v; v.f = f;
    return (u16)((v.u + 0x8000u) >> 16);
}
__device__ __forceinline__ float bf2f(u16 h) {
    union { unsigned u; float f; } v; v.u = ((unsigned)h) << 16;
    return v.f;
}

#define GLD16(g, l) __builtin_amdgcn_global_load_lds( \
    (const __attribute__((address_space(1))) void*)(g), \
    (__attribute__((address_space(3))) void*)(l), 16, 0, 0)

// ---------- x fp32 -> bf16 ; block 0 also zeroes the stats accumulator ----------
__global__ __launch_bounds__(256) void k_convx(const float* __restrict__ x,
                                               u16* __restrict__ xb,
                                               float* __restrict__ stats) {
    if (blockIdx.x == 0) {
        int t = threadIdx.x;
        stats[t] = 0.f; stats[256 + t] = 0.f; stats[512 + t] = 0.f; stats[768 + t] = 0.f;
    }
    size_t i = ((size_t)blockIdx.x * 256 + threadIdx.x) * 8;
    float4 a = *(const float4*)(x + i);
    float4 b = *(const float4*)(x + i + 4);
    u16x8 o;
    o[0]=f2bf(a.x); o[1]=f2bf(a.y); o[2]=f2bf(a.z); o[3]=f2bf(a.w);
    o[4]=f2bf(b.x); o[5]=f2bf(b.y); o[6]=f2bf(b.z); o[7]=f2bf(b.w);
    *(u16x8*)(xb + i) = o;
}

// ---------- W concat transpose+convert: wb[n][k] = W_seg[k][n&511], bf16 ----------
__global__ __launch_bounds__(256) void k_transw(const float* __restrict__ Wq,
                                                const float* __restrict__ Wk,
                                                const float* __restrict__ Wv,
                                                const float* __restrict__ Ws,
                                                u16* __restrict__ wb) {
    __shared__ float tile[64][65];
    int k0 = blockIdx.x * 64;
    int n0 = blockIdx.y * 64;
    const float* W = (n0 < 512) ? Wq : (n0 < 1024) ? Wk : (n0 < 1536) ? Wv : Ws;
    int col0 = n0 & 511;
    int t = threadIdx.x;
#pragma unroll
    for (int q = 0; q < 4; q++) {
        int idx = t + 256 * q;
        int row = idx >> 4, c4 = (idx & 15) * 4;
        float4 v = *(const float4*)&W[(size_t)(k0 + row) * 512 + col0 + c4];
        tile[row][c4 + 0] = v.x; tile[row][c4 + 1] = v.y;
        tile[row][c4 + 2] = v.z; tile[row][c4 + 3] = v.w;
    }
    __syncthreads();
#pragma unroll
    for (int q = 0; q < 2; q++) {
        int idx = t + 256 * q;
        int row = idx >> 3, c8 = (idx & 7) * 8;
        u16x8 o;
#pragma unroll
        for (int j = 0; j < 8; j++) o[j] = f2bf(tile[c8 + j][row]);
        *(u16x8*)&wb[(size_t)(n0 + row) * 4096 + k0 + c8] = o;
    }
}

// ---------- GEMM: qkvs[m][n] = bf16( (sum_k xb[m][k]*wb[n][k] + bias[n]) * scale_seg )
// Q segment pre-scaled by 0.125*log2(e) so attention scores are exp2-ready.
// V segment additionally written transposed to vt[n-1024][m].
__global__ __launch_bounds__(256) void k_gemm(const u16* __restrict__ xb,
                                              const u16* __restrict__ wb,
                                              const float* __restrict__ bq,
                                              const float* __restrict__ bk,
                                              const float* __restrict__ bv,
                                              const float* __restrict__ bs,
                                              u16* __restrict__ qkvs,
                                              u16* __restrict__ vt) {
    __shared__ __align__(16) u16 A_lds[128 * 32];
    __shared__ __align__(16) u16 B_lds[128 * 32];
    int tid = threadIdx.x;
    int w = tid >> 6, lane = tid & 63;
    int wr = w >> 1, wc = w & 1;
    int m0 = blockIdx.y * 128, n0 = blockIdx.x * 128;

    const f4 fz = {0.f, 0.f, 0.f, 0.f};
    f4 acc[4][4];
#pragma unroll
    for (int r = 0; r < 4; r++)
#pragma unroll
        for (int t = 0; t < 4; t++) acc[r][t] = fz;

    int srow = lane >> 2;
    int scol = (lane & 3) * 8;
    const u16* gA0 = xb + (size_t)(m0 + 32 * w + srow) * 4096 + scol;
    const u16* gB0 = wb + (size_t)(n0 + 32 * w + srow) * 4096 + scol;

    for (int kt = 0; kt < 128; ++kt) {
        int k0 = kt * 32;
        GLD16(gA0 + k0,             &A_lds[(32 * w) * 32]);
        GLD16(gA0 + k0 + 16 * 4096, &A_lds[(32 * w + 16) * 32]);
        GLD16(gB0 + k0,             &B_lds[(32 * w) * 32]);
        GLD16(gB0 + k0 + 16 * 4096, &B_lds[(32 * w + 16) * 32]);
        __syncthreads();
        s8v a[4], b[4];
#pragma unroll
        for (int r = 0; r < 4; r++)
            a[r] = *(const s8v*)&A_lds[(wr * 64 + 16 * r + (lane & 15)) * 32 + (lane >> 4) * 8];
#pragma unroll
        for (int t = 0; t < 4; t++)
            b[t] = *(const s8v*)&B_lds[(wc * 64 + 16 * t + (lane & 15)) * 32 + (lane >> 4) * 8];
#pragma unroll
        for (int r = 0; r < 4; r++)
#pragma unroll
            for (int t = 0; t < 4; t++)
                acc[r][t] = __builtin_amdgcn_mfma_f32_16x16x32_bf16(a[r], b[t], acc[r][t], 0, 0, 0);
        __syncthreads();
    }

#pragma unroll
    for (int t = 0; t < 4; t++) {
        int n = n0 + wc * 64 + 16 * t + (lane & 15);
        int seg = n >> 9, o = n & 511;
        const float* bp = (seg == 0) ? bq : (seg == 1) ? bk : (seg == 2) ? bv : bs;
        float bias = bp[o];
        float scale = (seg == 0) ? 0.1803368801f : 1.f;  // 0.125 * log2(e)
#pragma unroll
        for (int r = 0; r < 4; r++) {
            int mbase = m0 + wr * 64 + 16 * r + ((lane >> 4) << 2);
            u16x4 hv;
#pragma unroll
            for (int q2 = 0; q2 < 4; q2++) {
                u16 h = f2bf((acc[r][t][q2] + bias) * scale);
                hv[q2] = h;
                qkvs[(size_t)(mbase + q2) * 2048 + n] = h;
            }
            if (seg == 2)  // fused V transpose: vt[d][m], 4 contiguous m -> 8B store
                *(u16x4*)&vt[(size_t)(n - 1024) * 4096 + mbase] = hv;
        }
    }
}

// ---------- split-j max-free attention ----------
// block = (i-tile 64, head h, split sp); 4 waves, wave w owns rows 16w..16w+15.
// K/V'/Q staged via GLD16 into unpadded 64x64 tiles with XOR chunk swizzle.
// Q pre-scaled by 0.125*log2e: p = exp2(min(qk' + xx*qe', 115)) -- no running max
// (scores bounded far below fp32 overflow); partials o, l, sa are pure sums.
__global__ __launch_bounds__(256, 4) void k_attn(const u16* __restrict__ qkvs,
                                                 const u16* __restrict__ xb,
                                                 const u16* __restrict__ vt,
                                                 const float* __restrict__ we,
                                                 float* __restrict__ o_part,
                                                 float* __restrict__ lsa_part) {
    __shared__ __align__(16) u16 K_lds[64 * 64];  // swizzled (also Q staging)
    __shared__ __align__(16) u16 V_lds[64 * 64];  // swizzled, rows=d cols=j
    __shared__ __align__(16) u16 P_lds[64 * 72];  // padded, plain layout
    __shared__ __align__(16) u16 X_lds[64 * 72];  // padded bf16 x tile [j][i]
    __shared__ float qe8[64];

    int tid = threadIdx.x;
    int w = tid >> 6, lane = tid & 63;
    int L = lane & 15, q = lane >> 4;
    int i0 = blockIdx.x * 64;
    int h = blockIdx.y, hc = h * 64;
    int sp = blockIdx.z;

    int r8 = lane >> 3;                 // GLD16 source row within 8-row group
    int csw = ((lane & 7) ^ r8) * 8;    // XOR-swizzled source chunk (u16 units)

    // ---- stage Q into K_lds (GLD16, swizzled) ----
    {
        const u16* g0 = qkvs + (size_t)i0 * 2048 + hc;
#pragma unroll
        for (int ih = 0; ih < 2; ih++) {
            int rb = 16 * w + 8 * ih;
            GLD16(g0 + (size_t)(rb + r8) * 2048 + csw, &K_lds[rb * 64]);
        }
    }
    __syncthreads();

    s8v qf[2];
#pragma unroll
    for (int c = 0; c < 2; c++) {
        int row = 16 * w + L;
        qf[c] = *(const s8v*)&K_lds[row * 64 + (((4 * c + q) ^ (row & 7)) * 8)];
    }
    if (tid < 64) {  // qe8[i] = q'_i . we_h   (q' already carries 0.125*log2e)
        float s = 0.f;
        int r7 = tid & 7;
#pragma unroll
        for (int d = 0; d < 64; d++)
            s += bf2f(K_lds[tid * 64 + ((d >> 3) ^ r7) * 8 + (d & 7)]) * we[hc + d];
        qe8[tid] = s;
    }
    __syncthreads();

    float qe_r[4];
#pragma unroll
    for (int r = 0; r < 4; r++) qe_r[r] = qe8[16 * w + 4 * q + r];

    const f4 fz = {0.f, 0.f, 0.f, 0.f};
    f4 o_acc[4];
    float l_p[4], sa_p[4];
#pragma unroll
    for (int r = 0; r < 4; r++) { l_p[r] = 0.f; sa_p[r] = 0.f; }
#pragma unroll
    for (int t = 0; t < 4; t++) o_acc[t] = fz;

    for (int jt64 = 0; jt64 < 32; ++jt64) {
        int j0 = sp * 2048 + jt64 * 64;
        // stage K (GLD16)
        {
            const u16* g0 = qkvs + (size_t)j0 * 2048 + 512 + hc;
#pragma unroll
            for (int ih = 0; ih < 2; ih++) {
                int rb = 16 * w + 8 * ih;
                GLD16(g0 + (size_t)(rb + r8) * 2048 + csw, &K_lds[rb * 64]);
            }
        }
        // stage V^T (GLD16): rows are d, cols j
        {
            const u16* g0 = vt + (size_t)hc * 4096 + j0;
#pragma unroll
            for (int ih = 0; ih < 2; ih++) {
                int rb = 16 * w + 8 * ih;
                GLD16(g0 + (size_t)(rb + r8) * 4096 + csw, &V_lds[rb * 64]);
            }
        }
        // stage X tile bf16: X_lds[j][i] (padded 72, plain)
#pragma unroll
        for (int qq = 0; qq < 2; qq++) {
            int idx = tid + 256 * qq;
            int row = idx >> 3, c8 = (idx & 7) * 8;
            *(s8v*)&X_lds[row * 72 + c8] =
                *(const s8v*)&xb[(size_t)(j0 + row) * 4096 + i0 + c8];
        }
        __syncthreads();

#pragma unroll
        for (int jt = 0; jt < 4; jt++) {
            int n = L + 16 * jt;
            int n7 = n & 7;
            s8v b0 = *(const s8v*)&K_lds[n * 64 + ((q ^ n7) * 8)];
            s8v b1 = *(const s8v*)&K_lds[n * 64 + (((4 + q) ^ n7) * 8)];
            f4 acc = fz;
            acc = __builtin_amdgcn_mfma_f32_16x16x32_bf16(qf[0], b0, acc, 0, 0, 0);
            acc = __builtin_amdgcn_mfma_f32_16x16x32_bf16(qf[1], b1, acc, 0, 0, 0);
            u16x4 xv4 = *(const u16x4*)&X_lds[n * 72 + 16 * w + 4 * q];
#pragma unroll
            for (int r = 0; r < 4; r++) {
                float xx = bf2f(xv4[r]);
                float s = fminf(acc[r] + xx * qe_r[r], 115.f);   // log2 units
                float p = __builtin_amdgcn_exp2f(s);
                l_p[r] += p;
                sa_p[r] += p * xx;
                P_lds[(16 * w + 4 * q + r) * 72 + n] = f2bf_hu(p);
            }
        }

        // PV (wave-local P round-trip; same-wave rows only)
        {
            int row = 16 * w + L;
            s8v a0 = *(const s8v*)&P_lds[row * 72 + q * 8];
            s8v a1 = *(const s8v*)&P_lds[row * 72 + 32 + q * 8];
#pragma unroll
            for (int t = 0; t < 4; t++) {
                int n = L + 16 * t;
                int n7 = n & 7;
                s8v b0 = *(const s8v*)&V_lds[n * 64 + ((q ^ n7) * 8)];
                s8v b1 = *(const s8v*)&V_lds[n * 64 + (((4 + q) ^ n7) * 8)];
                o_acc[t] = __builtin_amdgcn_mfma_f32_16x16x32_bf16(a0, b0, o_acc[t], 0, 0, 0);
                o_acc[t] = __builtin_amdgcn_mfma_f32_16x16x32_bf16(a1, b1, o_acc[t], 0, 0, 0);
            }
        }
        __syncthreads();
    }

    // epilogue: write raw partials (division happens in k_comb after summing l)
#pragma unroll
    for (int r = 0; r < 4; r++) {
        float l = l_p[r], sa = sa_p[r];
        l += __shfl_xor(l, 1);  sa += __shfl_xor(sa, 1);
        l += __shfl_xor(l, 2);  sa += __shfl_xor(sa, 2);
        l += __shfl_xor(l, 4);  sa += __shfl_xor(sa, 4);
        l += __shfl_xor(l, 8);  sa += __shfl_xor(sa, 8);
        int i = i0 + 16 * w + 4 * q + r;
#pragma unroll
        for (int t = 0; t < 4; t++)
            o_part[((size_t)sp * 4096 + i) * 512 + hc + L + 16 * t] = o_acc[t][r];
        if (L == 0) {
            size_t bi = (((size_t)sp * 4096 + i) * 8 + h) * 2;
            lsa_part[bi] = l;
            lsa_part[bi + 1] = sa;
        }
    }
}

// ---------- combine splits + skip + out_pre + column stats ----------
__global__ __launch_bounds__(512) void k_comb(const float* __restrict__ o_part,
                                              const float* __restrict__ lsa,
                                              const u16* __restrict__ qkvs,
                                              const float* __restrict__ we,
                                              float* __restrict__ out_pre,
                                              float* __restrict__ stats) {
    int c = threadIdx.x;
    int r0 = blockIdx.x * 64;
    int h = c >> 6;
    float wec = we[c];
    float s = 0.f, s2 = 0.f;
    for (int ii = 0; ii < 64; ii++) {
        int i = r0 + ii;
        size_t b0 = ((size_t)i * 8 + h) * 2;
        size_t b1 = (((size_t)4096 + i) * 8 + h) * 2;
        float l = lsa[b0] + lsa[b1];
        float sa = lsa[b0 + 1] + lsa[b1 + 1];
        float o = o_part[(size_t)i * 512 + c] + o_part[((size_t)4096 + i) * 512 + c];
        float inv = 1.f / l;
        float v = (o + sa * wec) * inv + bf2f(qkvs[(size_t)i * 2048 + 1536 + c]);
        out_pre[(size_t)i * 512 + c] = v;
        s += v; s2 += v * v;
    }
    atomicAdd(&stats[c], s);
    atomicAdd(&stats[512 + c], s2);
}

// ---------- GraphNorm + per-row L2 normalize ----------
__global__ __launch_bounds__(512) void k_final(const float* __restrict__ out_pre,
                                               const float* __restrict__ stats,
                                               const float* __restrict__ gn_w,
                                               const float* __restrict__ gn_b,
                                               const float* __restrict__ gn_ms,
                                               float* __restrict__ out) {
    __shared__ float red[8];
    int c = threadIdx.x;
    int i = blockIdx.x;
    float mean = stats[c] * (1.f / 4096.f);
    float ex2 = stats[512 + c] * (1.f / 4096.f);
    float g = gn_ms[c];
    float var = ex2 - (2.f * g - g * g) * mean * mean;
    float y = gn_w[c] * (out_pre[(size_t)i * 512 + c] - g * mean) * rsqrtf(var + 1e-5f) + gn_b[c];
    float qv = y * y;
    qv += __shfl_xor(qv, 1);  qv += __shfl_xor(qv, 2);  qv += __shfl_xor(qv, 4);
    qv += __shfl_xor(qv, 8);  qv += __shfl_xor(qv, 16); qv += __shfl_xor(qv, 32);
    if ((c & 63) == 0) red[c >> 6] = qv;
    __syncthreads();
    float tot = 0.f;
#pragma unroll
    for (int k = 0; k < 8; k++) tot += red[k];
    out[(size_t)i * 512 + c] = y * rsqrtf(tot);
}

extern "C" void kernel_launch(void* const* d_in, const int* in_sizes, int n_in,
                              void* d_out, int out_size, void* d_ws, size_t ws_size,
                              hipStream_t stream) {
    (void)in_sizes; (void)n_in; (void)out_size; (void)ws_size;
    const float* x    = (const float*)d_in[0];
    const float* Wq   = (const float*)d_in[1];
    const float* bq   = (const float*)d_in[2];
    const float* Wk   = (const float*)d_in[3];
    const float* bk   = (const float*)d_in[4];
    const float* Wv   = (const float*)d_in[5];
    const float* bv   = (const float*)d_in[6];
    const float* we   = (const float*)d_in[7];
    const float* Ws   = (const float*)d_in[8];
    const float* bs   = (const float*)d_in[9];
    const float* gnw  = (const float*)d_in[10];
    const float* gnb  = (const float*)d_in[11];
    const float* gnms = (const float*)d_in[12];
    float* out = (float*)d_out;

    char* ws = (char*)d_ws;
    // Region reuse (all launches sequential on `stream`):
    //   [0,32M):   xb (convx..attn) then out_pre overlays (comb..final)
    //   [32M,48M): wb (transw..gemm) then o_part overlays (attn..comb)
    //   [48M,64M): qkvs (gemm..comb)
    //   [64M,68M): vt (gemm..attn)
    //   [68M,+512K): lsa_part ; stats after it
    u16* xb        = (u16*)(ws);
    float* out_pre = (float*)(ws);
    u16* wb        = (u16*)(ws + (size_t)33554432);
    float* o_part  = (float*)(ws + (size_t)33554432);
    u16* qkvs      = (u16*)(ws + (size_t)50331648);
    u16* vt        = (u16*)(ws + (size_t)67108864);
    float* lsa     = (float*)(ws + (size_t)71303168);
    float* stats   = (float*)(ws + (size_t)71303168 + 524288);

    k_convx<<<8192, 256, 0, stream>>>(x, xb, stats);
    k_transw<<<dim3(64, 32), 256, 0, stream>>>(Wq, Wk, Wv, Ws, wb);
    k_gemm<<<dim3(16, 32), 256, 0, stream>>>(xb, wb, bq, bk, bv, bs, qkvs, vt);
    k_attn<<<dim3(64, 8, 2), 256, 0, stream>>>(qkvs, xb, vt, we, o_part, lsa);
    k_comb<<<64, 512, 0, stream>>>(o_part, lsa, qkvs, we, out_pre, stats);
    k_final<<<4096, 512, 0, stream>>>(out_pre, stats, gnw, gnb, gnms, out);
}

// Round 5
// 328.625 us; speedup vs baseline: 1.5840x; 1.0264x over previous
//
#include <hip/hip_runtime.h>

// N=4096 nodes, H=8 heads, D=64, C=512. All fp32 in, fp32 out.
// Pipeline: convert(+stat zero) -> GEMM(qkv+skip, Q pre-scaled by 0.125*log2e,
// V also written transposed) -> split-j max-free flash attn (exp2 path) ->
// combine(+skip+stats) -> GraphNorm+L2.

typedef short s8v __attribute__((ext_vector_type(8)));       // 8 bf16 (A/B frag)
typedef unsigned short u16x8 __attribute__((ext_vector_type(8)));
typedef unsigned short u16x4 __attribute__((ext_vector_type(4)));
typedef float f4 __attribute__((ext_vector_type(4)));        // C/D frag
typedef unsigned short u16;

__device__ __forceinline__ u16 f2bf(float f) {               // RNE (cold paths)
    union { float f; unsigned u; } v; v.f = f;
    unsigned r = v.u + 0x7fffu + ((v.u >> 16) & 1u);
    return (u16)(r >> 16);
}
__device__ __forceinline__ u16 f2bf_hu(float f) {            // round-half-up, 2 ops (P>=0)
    union { float f; unsigned u; } v; v.f = f;
    return (u16)((v.u + 0x8000u) >> 16);
}
__device__ __forceinline__ float bf2f(u16 h) {
    union { unsigned u; float f; } v; v.u = ((unsigned)h) << 16;
    return v.f;
}

#define GLD16(g, l) __builtin_amdgcn_global_load_lds( \
    (const __attribute__((address_space(1))) void*)(g), \
    (__attribute__((address_space(3))) void*)(l), 16, 0, 0)

// ---------- x fp32 -> bf16 ; block 0 also zeroes the stats accumulator ----------
__global__ __launch_bounds__(256) void k_convx(const float* __restrict__ x,
                                               u16* __restrict__ xb,
                                               float* __restrict__ stats) {
    if (blockIdx.x == 0) {
        int t = threadIdx.x;
        stats[t] = 0.f; stats[256 + t] = 0.f; stats[512 + t] = 0.f; stats[768 + t] = 0.f;
    }
    size_t i = ((size_t)blockIdx.x * 256 + threadIdx.x) * 8;
    float4 a = *(const float4*)(x + i);
    float4 b = *(const float4*)(x + i + 4);
    u16x8 o;
    o[0]=f2bf(a.x); o[1]=f2bf(a.y); o[2]=f2bf(a.z); o[3]=f2bf(a.w);
    o[4]=f2bf(b.x); o[5]=f2bf(b.y); o[6]=f2bf(b.z); o[7]=f2bf(b.w);
    *(u16x8*)(xb + i) = o;
}

// ---------- W concat transpose+convert: wb[n][k] = W_seg[k][n&511], bf16 ----------
__global__ __launch_bounds__(256) void k_transw(const float* __restrict__ Wq,
                                                const float* __restrict__ Wk,
                                                const float* __restrict__ Wv,
                                                const float* __restrict__ Ws,
                                                u16* __restrict__ wb) {
    __shared__ float tile[64][65];
    int k0 = blockIdx.x * 64;
    int n0 = blockIdx.y * 64;
    const float* W = (n0 < 512) ? Wq : (n0 < 1024) ? Wk : (n0 < 1536) ? Wv : Ws;
    int col0 = n0 & 511;
    int t = threadIdx.x;
#pragma unroll
    for (int q = 0; q < 4; q++) {
        int idx = t + 256 * q;
        int row = idx >> 4, c4 = (idx & 15) * 4;
        float4 v = *(const float4*)&W[(size_t)(k0 + row) * 512 + col0 + c4];
        tile[row][c4 + 0] = v.x; tile[row][c4 + 1] = v.y;
        tile[row][c4 + 2] = v.z; tile[row][c4 + 3] = v.w;
    }
    __syncthreads();
#pragma unroll
    for (int q = 0; q < 2; q++) {
        int idx = t + 256 * q;
        int row = idx >> 3, c8 = (idx & 7) * 8;
        u16x8 o;
#pragma unroll
        for (int j = 0; j < 8; j++) o[j] = f2bf(tile[c8 + j][row]);
        *(u16x8*)&wb[(size_t)(n0 + row) * 4096 + k0 + c8] = o;
    }
}

// ---------- GEMM: qkvs[m][n] = bf16( (sum_k xb[m][k]*wb[n][k] + bias[n]) * scale_seg )
// BK=64: LDS rows are 64 u16 = 128 B = 8 x 16B chunks, XOR-swizzled
// (LDS[row][c] holds global chunk c^(row&7)) -> conflict-free b128 frag reads
// (same verified geometry as k_attn). Q pre-scaled by 0.125*log2e;
// V additionally written transposed to vt[n-1024][m].
__global__ __launch_bounds__(256) void k_gemm(const u16* __restrict__ xb,
                                              const u16* __restrict__ wb,
                                              const float* __restrict__ bq,
                                              const float* __restrict__ bk,
                                              const float* __restrict__ bv,
                                              const float* __restrict__ bs,
                                              u16* __restrict__ qkvs,
                                              u16* __restrict__ vt) {
    __shared__ __align__(16) u16 A_lds[128 * 64];
    __shared__ __align__(16) u16 B_lds[128 * 64];
    int tid = threadIdx.x;
    int w = tid >> 6, lane = tid & 63;
    int wr = w >> 1, wc = w & 1;
    int L = lane & 15, q = lane >> 4;
    int m0 = blockIdx.y * 128, n0 = blockIdx.x * 128;

    const f4 fz = {0.f, 0.f, 0.f, 0.f};
    f4 acc[4][4];
#pragma unroll
    for (int r = 0; r < 4; r++)
#pragma unroll
        for (int t = 0; t < 4; t++) acc[r][t] = fz;

    int r8 = lane >> 3;                 // source row within 8-row group
    int csw = ((lane & 7) ^ r8) * 8;    // XOR-swizzled source chunk (u16 units)
    const u16* gA0 = xb + (size_t)(m0 + r8) * 4096 + csw;
    const u16* gB0 = wb + (size_t)(n0 + r8) * 4096 + csw;

    for (int kt = 0; kt < 64; ++kt) {
        int k0 = kt * 64;
#pragma unroll
        for (int g = 0; g < 4; g++) {
            int rb = 32 * w + 8 * g;
            GLD16(gA0 + (size_t)rb * 4096 + k0, &A_lds[rb * 64]);
            GLD16(gB0 + (size_t)rb * 4096 + k0, &B_lds[rb * 64]);
        }
        __syncthreads();
        s8v a[4][2], b[4][2];
#pragma unroll
        for (int r = 0; r < 4; r++) {
            int row = wr * 64 + 16 * r + L;
            int r7 = row & 7;
            a[r][0] = *(const s8v*)&A_lds[row * 64 + ((q ^ r7) * 8)];
            a[r][1] = *(const s8v*)&A_lds[row * 64 + (((4 + q) ^ r7) * 8)];
        }
#pragma unroll
        for (int t = 0; t < 4; t++) {
            int row = wc * 64 + 16 * t + L;
            int r7 = row & 7;
            b[t][0] = *(const s8v*)&B_lds[row * 64 + ((q ^ r7) * 8)];
            b[t][1] = *(const s8v*)&B_lds[row * 64 + (((4 + q) ^ r7) * 8)];
        }
#pragma unroll
        for (int r = 0; r < 4; r++)
#pragma unroll
            for (int t = 0; t < 4; t++) {
                acc[r][t] = __builtin_amdgcn_mfma_f32_16x16x32_bf16(a[r][0], b[t][0], acc[r][t], 0, 0, 0);
                acc[r][t] = __builtin_amdgcn_mfma_f32_16x16x32_bf16(a[r][1], b[t][1], acc[r][t], 0, 0, 0);
            }
        __syncthreads();
    }

#pragma unroll
    for (int t = 0; t < 4; t++) {
        int n = n0 + wc * 64 + 16 * t + L;
        int seg = n >> 9, o = n & 511;
        const float* bp = (seg == 0) ? bq : (seg == 1) ? bk : (seg == 2) ? bv : bs;
        float bias = bp[o];
        float scale = (seg == 0) ? 0.1803368801f : 1.f;  // 0.125 * log2(e)
#pragma unroll
        for (int r = 0; r < 4; r++) {
            int mbase = m0 + wr * 64 + 16 * r + 4 * q;
            u16x4 hv;
#pragma unroll
            for (int q2 = 0; q2 < 4; q2++) {
                u16 hb = f2bf((acc[r][t][q2] + bias) * scale);
                hv[q2] = hb;
                qkvs[(size_t)(mbase + q2) * 2048 + n] = hb;
            }
            if (seg == 2)  // fused V transpose: vt[d][m], 4 contiguous m -> 8B store
                *(u16x4*)&vt[(size_t)(n - 1024) * 4096 + mbase] = hv;
        }
    }
}

// ---------- split-j max-free attention ----------
// block = (i-tile 64, head h, split sp); 4 waves, wave w owns rows 16w..16w+15.
// K/V'/Q staged via GLD16 into unpadded 64x64 tiles with XOR chunk swizzle.
// Q pre-scaled by 0.125*log2e: p = exp2(min(qk' + xx*qe', 115)) -- no running max
// (scores bounded far below fp32 overflow); partials o, l, sa are pure sums.
__global__ __launch_bounds__(256, 4) void k_attn(const u16* __restrict__ qkvs,
                                                 const u16* __restrict__ xb,
                                                 const u16* __restrict__ vt,
                                                 const float* __restrict__ we,
                                                 float* __restrict__ o_part,
                                                 float* __restrict__ lsa_part) {
    __shared__ __align__(16) u16 K_lds[64 * 64];  // swizzled (also Q staging)
    __shared__ __align__(16) u16 V_lds[64 * 64];  // swizzled, rows=d cols=j
    __shared__ __align__(16) u16 P_lds[64 * 72];  // padded, plain layout
    __shared__ __align__(16) u16 X_lds[64 * 72];  // padded bf16 x tile [j][i]
    __shared__ float qe8[64];

    int tid = threadIdx.x;
    int w = tid >> 6, lane = tid & 63;
    int L = lane & 15, q = lane >> 4;
    int i0 = blockIdx.x * 64;
    int h = blockIdx.y, hc = h * 64;
    int sp = blockIdx.z;

    int r8 = lane >> 3;                 // GLD16 source row within 8-row group
    int csw = ((lane & 7) ^ r8) * 8;    // XOR-swizzled source chunk (u16 units)

    // ---- stage Q into K_lds (GLD16, swizzled) ----
    {
        const u16* g0 = qkvs + (size_t)i0 * 2048 + hc;
#pragma unroll
        for (int ih = 0; ih < 2; ih++) {
            int rb = 16 * w + 8 * ih;
            GLD16(g0 + (size_t)(rb + r8) * 2048 + csw, &K_lds[rb * 64]);
        }
    }
    __syncthreads();

    s8v qf[2];
#pragma unroll
    for (int c = 0; c < 2; c++) {
        int row = 16 * w + L;
        qf[c] = *(const s8v*)&K_lds[row * 64 + (((4 * c + q) ^ (row & 7)) * 8)];
    }
    if (tid < 64) {  // qe8[i] = q'_i . we_h   (q' already carries 0.125*log2e)
        float s = 0.f;
        int r7 = tid & 7;
#pragma unroll
        for (int d = 0; d < 64; d++)
            s += bf2f(K_lds[tid * 64 + ((d >> 3) ^ r7) * 8 + (d & 7)]) * we[hc + d];
        qe8[tid] = s;
    }
    __syncthreads();

    float qe_r[4];
#pragma unroll
    for (int r = 0; r < 4; r++) qe_r[r] = qe8[16 * w + 4 * q + r];

    const f4 fz = {0.f, 0.f, 0.f, 0.f};
    f4 o_acc[4];
    float l_p[4], sa_p[4];
#pragma unroll
    for (int r = 0; r < 4; r++) { l_p[r] = 0.f; sa_p[r] = 0.f; }
#pragma unroll
    for (int t = 0; t < 4; t++) o_acc[t] = fz;

    for (int jt64 = 0; jt64 < 32; ++jt64) {
        int j0 = sp * 2048 + jt64 * 64;
        // stage K (GLD16)
        {
            const u16* g0 = qkvs + (size_t)j0 * 2048 + 512 + hc;
#pragma unroll
            for (int ih = 0; ih < 2; ih++) {
                int rb = 16 * w + 8 * ih;
                GLD16(g0 + (size_t)(rb + r8) * 2048 + csw, &K_lds[rb * 64]);
            }
        }
        // stage V^T (GLD16): rows are d, cols j
        {
            const u16* g0 = vt + (size_t)hc * 4096 + j0;
#pragma unroll
            for (int ih = 0; ih < 2; ih++) {
                int rb = 16 * w + 8 * ih;
                GLD16(g0 + (size_t)(rb + r8) * 4096 + csw, &V_lds[rb * 64]);
            }
        }
        // stage X tile bf16: X_lds[j][i] (padded 72, plain)
#pragma unroll
        for (int qq = 0; qq < 2; qq++) {
            int idx = tid + 256 * qq;
            int row = idx >> 3, c8 = (idx & 7) * 8;
            *(s8v*)&X_lds[row * 72 + c8] =
                *(const s8v*)&xb[(size_t)(j0 + row) * 4096 + i0 + c8];
        }
        __syncthreads();

#pragma unroll
        for (int jt = 0; jt < 4; jt++) {
            int n = L + 16 * jt;
            int n7 = n & 7;
            s8v b0 = *(const s8v*)&K_lds[n * 64 + ((q ^ n7) * 8)];
            s8v b1 = *(const s8v*)&K_lds[n * 64 + (((4 + q) ^ n7) * 8)];
            f4 acc = fz;
            acc = __builtin_amdgcn_mfma_f32_16x16x32_bf16(qf[0], b0, acc, 0, 0, 0);
            acc = __builtin_amdgcn_mfma_f32_16x16x32_bf16(qf[1], b1, acc, 0, 0, 0);
            u16x4 xv4 = *(const u16x4*)&X_lds[n * 72 + 16 * w + 4 * q];
#pragma unroll
            for (int r = 0; r < 4; r++) {
                float xx = bf2f(xv4[r]);
                float s = fminf(acc[r] + xx * qe_r[r], 115.f);   // log2 units
                float p = __builtin_amdgcn_exp2f(s);
                l_p[r] += p;
                sa_p[r] += p * xx;
                P_lds[(16 * w + 4 * q + r) * 72 + n] = f2bf_hu(p);
            }
        }

        // PV (wave-local P round-trip; same-wave rows only)
        {
            int row = 16 * w + L;
            s8v a0 = *(const s8v*)&P_lds[row * 72 + q * 8];
            s8v a1 = *(const s8v*)&P_lds[row * 72 + 32 + q * 8];
#pragma unroll
            for (int t = 0; t < 4; t++) {
                int n = L + 16 * t;
                int n7 = n & 7;
                s8v b0 = *(const s8v*)&V_lds[n * 64 + ((q ^ n7) * 8)];
                s8v b1 = *(const s8v*)&V_lds[n * 64 + (((4 + q) ^ n7) * 8)];
                o_acc[t] = __builtin_amdgcn_mfma_f32_16x16x32_bf16(a0, b0, o_acc[t], 0, 0, 0);
                o_acc[t] = __builtin_amdgcn_mfma_f32_16x16x32_bf16(a1, b1, o_acc[t], 0, 0, 0);
            }
        }
        __syncthreads();
    }

    // epilogue: write raw partials (division happens in k_comb after summing l)
#pragma unroll
    for (int r = 0; r < 4; r++) {
        float l = l_p[r], sa = sa_p[r];
        l += __shfl_xor(l, 1);  sa += __shfl_xor(sa, 1);
        l += __shfl_xor(l, 2);  sa += __shfl_xor(sa, 2);
        l += __shfl_xor(l, 4);  sa += __shfl_xor(sa, 4);
        l += __shfl_xor(l, 8);  sa += __shfl_xor(sa, 8);
        int i = i0 + 16 * w + 4 * q + r;
#pragma unroll
        for (int t = 0; t < 4; t++)
            o_part[((size_t)sp * 4096 + i) * 512 + hc + L + 16 * t] = o_acc[t][r];
        if (L == 0) {
            size_t bi = (((size_t)sp * 4096 + i) * 8 + h) * 2;
            lsa_part[bi] = l;
            lsa_part[bi + 1] = sa;
        }
    }
}

// ---------- combine splits + skip + out_pre + column stats ----------
__global__ __launch_bounds__(512) void k_comb(const float* __restrict__ o_part,
                                              const float* __restrict__ lsa,
                                              const u16* __restrict__ qkvs,
                                              const float* __restrict__ we,
                                              float* __restrict__ out_pre,
                                              float* __restrict__ stats) {
    int c = threadIdx.x;
    int r0 = blockIdx.x * 64;
    int h = c >> 6;
    float wec = we[c];
    float s = 0.f, s2 = 0.f;
    for (int ii = 0; ii < 64; ii++) {
        int i = r0 + ii;
        size_t b0 = ((size_t)i * 8 + h) * 2;
        size_t b1 = (((size_t)4096 + i) * 8 + h) * 2;
        float l = lsa[b0] + lsa[b1];
        float sa = lsa[b0 + 1] + lsa[b1 + 1];
        float o = o_part[(size_t)i * 512 + c] + o_part[((size_t)4096 + i) * 512 + c];
        float inv = 1.f / l;
        float v = (o + sa * wec) * inv + bf2f(qkvs[(size_t)i * 2048 + 1536 + c]);
        out_pre[(size_t)i * 512 + c] = v;
        s += v; s2 += v * v;
    }
    atomicAdd(&stats[c], s);
    atomicAdd(&stats[512 + c], s2);
}

// ---------- GraphNorm + per-row L2 normalize ----------
__global__ __launch_bounds__(512) void k_final(const float* __restrict__ out_pre,
                                               const float* __restrict__ stats,
                                               const float* __restrict__ gn_w,
                                               const float* __restrict__ gn_b,
                                               const float* __restrict__ gn_ms,
                                               float* __restrict__ out) {
    __shared__ float red[8];
    int c = threadIdx.x;
    int i = blockIdx.x;
    float mean = stats[c] * (1.f / 4096.f);
    float ex2 = stats[512 + c] * (1.f / 4096.f);
    float g = gn_ms[c];
    float var = ex2 - (2.f * g - g * g) * mean * mean;
    float y = gn_w[c] * (out_pre[(size_t)i * 512 + c] - g * mean) * rsqrtf(var + 1e-5f) + gn_b[c];
    float qv = y * y;
    qv += __shfl_xor(qv, 1);  qv += __shfl_xor(qv, 2);  qv += __shfl_xor(qv, 4);
    qv += __shfl_xor(qv, 8);  qv += __shfl_xor(qv, 16); qv += __shfl_xor(qv, 32);
    if ((c & 63) == 0) red[c >> 6] = qv;
    __syncthreads();
    float tot = 0.f;
#pragma unroll
    for (int k = 0; k < 8; k++) tot += red[k];
    out[(size_t)i * 512 + c] = y * rsqrtf(tot);
}

extern "C" void kernel_launch(void* const* d_in, const int* in_sizes, int n_in,
                              void* d_out, int out_size, void* d_ws, size_t ws_size,
                              hipStream_t stream) {
    (void)in_sizes; (void)n_in; (void)out_size; (void)ws_size;
    const float* x    = (const float*)d_in[0];
    const float* Wq   = (const float*)d_in[1];
    const float* bq   = (const float*)d_in[2];
    const float* Wk   = (const float*)d_in[3];
    const float* bk   = (const float*)d_in[4];
    const float* Wv   = (const float*)d_in[5];
    const float* bv   = (const float*)d_in[6];
    const float* we   = (const float*)d_in[7];
    const float* Ws   = (const float*)d_in[8];
    const float* bs   = (const float*)d_in[9];
    const float* gnw  = (const float*)d_in[10];
    const float* gnb  = (const float*)d_in[11];
    const float* gnms = (const float*)d_in[12];
    float* out = (float*)d_out;

    char* ws = (char*)d_ws;
    // Region reuse (all launches sequential on `stream`):
    //   [0,32M):   xb (convx..attn) then out_pre overlays (comb..final)
    //   [32M,48M): wb (transw..gemm) then o_part overlays (attn..comb)
    //   [48M,64M): qkvs (gemm..comb)
    //   [64M,68M): vt (gemm..attn)
    //   [68M,+512K): lsa_part ; stats after it
    u16* xb        = (u16*)(ws);
    float* out_pre = (float*)(ws);
    u16* wb        = (u16*)(ws + (size_t)33554432);
    float* o_part  = (float*)(ws + (size_t)33554432);
    u16* qkvs      = (u16*)(ws + (size_t)50331648);
    u16* vt        = (u16*)(ws + (size_t)67108864);
    float* lsa     = (float*)(ws + (size_t)71303168);
    float* stats   = (float*)(ws + (size_t)71303168 + 524288);

    k_convx<<<8192, 256, 0, stream>>>(x, xb, stats);
    k_transw<<<dim3(64, 32), 256, 0, stream>>>(Wq, Wk, Wv, Ws, wb);
    k_gemm<<<dim3(16, 32), 256, 0, stream>>>(xb, wb, bq, bk, bv, bs, qkvs, vt);
    k_attn<<<dim3(64, 8, 2), 256, 0, stream>>>(qkvs, xb, vt, we, o_part, lsa);
    k_comb<<<64, 512, 0, stream>>>(o_part, lsa, qkvs, we, out_pre, stats);
    k_final<<<4096, 512, 0, stream>>>(out_pre, stats, gnw, gnb, gnms, out);
}

// Round 6
// 311.635 us; speedup vs baseline: 1.6704x; 1.0545x over previous
//
#include <hip/hip_runtime.h>

// N=4096 nodes, H=8 heads, D=64, C=512. All fp32 in, fp32 out.
// Pipeline: convert(+stat zero) -> GEMM(qkv+skip, Q pre-scaled by 0.125*log2e,
// V also written transposed) -> split-j max-free flash attn (exp2 path) ->
// combine(+skip+stats) -> GraphNorm+L2.

typedef short s8v __attribute__((ext_vector_type(8)));       // 8 bf16 (A/B frag)
typedef unsigned short u16x8 __attribute__((ext_vector_type(8)));
typedef unsigned short u16x4 __attribute__((ext_vector_type(4)));
typedef float f4 __attribute__((ext_vector_type(4)));        // C/D frag
typedef unsigned short u16;

__device__ __forceinline__ u16 f2bf(float f) {               // RNE (cold paths)
    union { float f; unsigned u; } v; v.f = f;
    unsigned r = v.u + 0x7fffu + ((v.u >> 16) & 1u);
    return (u16)(r >> 16);
}
__device__ __forceinline__ u16 f2bf_hu(float f) {            // round-half-up, 2 ops (P>=0)
    union { float f; unsigned u; } v; v.f = f;
    return (u16)((v.u + 0x8000u) >> 16);
}
__device__ __forceinline__ float bf2f(u16 h) {
    union { unsigned u; float f; } v; v.u = ((unsigned)h) << 16;
    return v.f;
}

#define GLD16(g, l) __builtin_amdgcn_global_load_lds( \
    (const __attribute__((address_space(1))) void*)(g), \
    (__attribute__((address_space(3))) void*)(l), 16, 0, 0)

// ---------- x fp32 -> bf16 ; block 0 also zeroes the stats accumulator ----------
__global__ __launch_bounds__(256) void k_convx(const float* __restrict__ x,
                                               u16* __restrict__ xb,
                                               float* __restrict__ stats) {
    if (blockIdx.x == 0) {
        int t = threadIdx.x;
        stats[t] = 0.f; stats[256 + t] = 0.f; stats[512 + t] = 0.f; stats[768 + t] = 0.f;
    }
    size_t i = ((size_t)blockIdx.x * 256 + threadIdx.x) * 8;
    float4 a = *(const float4*)(x + i);
    float4 b = *(const float4*)(x + i + 4);
    u16x8 o;
    o[0]=f2bf(a.x); o[1]=f2bf(a.y); o[2]=f2bf(a.z); o[3]=f2bf(a.w);
    o[4]=f2bf(b.x); o[5]=f2bf(b.y); o[6]=f2bf(b.z); o[7]=f2bf(b.w);
    *(u16x8*)(xb + i) = o;
}

// ---------- W concat transpose+convert: wb[n][k] = W_seg[k][n&511], bf16 ----------
__global__ __launch_bounds__(256) void k_transw(const float* __restrict__ Wq,
                                                const float* __restrict__ Wk,
                                                const float* __restrict__ Wv,
                                                const float* __restrict__ Ws,
                                                u16* __restrict__ wb) {
    __shared__ float tile[64][65];
    int k0 = blockIdx.x * 64;
    int n0 = blockIdx.y * 64;
    const float* W = (n0 < 512) ? Wq : (n0 < 1024) ? Wk : (n0 < 1536) ? Wv : Ws;
    int col0 = n0 & 511;
    int t = threadIdx.x;
#pragma unroll
    for (int q = 0; q < 4; q++) {
        int idx = t + 256 * q;
        int row = idx >> 4, c4 = (idx & 15) * 4;
        float4 v = *(const float4*)&W[(size_t)(k0 + row) * 512 + col0 + c4];
        tile[row][c4 + 0] = v.x; tile[row][c4 + 1] = v.y;
        tile[row][c4 + 2] = v.z; tile[row][c4 + 3] = v.w;
    }
    __syncthreads();
#pragma unroll
    for (int q = 0; q < 2; q++) {
        int idx = t + 256 * q;
        int row = idx >> 3, c8 = (idx & 7) * 8;
        u16x8 o;
#pragma unroll
        for (int j = 0; j < 8; j++) o[j] = f2bf(tile[c8 + j][row]);
        *(u16x8*)&wb[(size_t)(n0 + row) * 4096 + k0 + c8] = o;
    }
}

// ---------- GEMM: qkvs[m][n] = bf16( (sum_k xb[m][k]*wb[n][k] + bias[n]) * scale_seg )
// 128x128 tile, BK=64 (rows = 128 B = 8 chunks, XOR-swizzled -> 0 conflicts,
// verified R5). 512 threads / 8 waves per block: grid is only 2 blocks/CU, so
// 8-wave blocks give 16 waves/CU (vs 8) to hide the vmcnt+barrier drain.
// Wave w: rows 32*(w>>1), cols 64*(w&1); 2x4 acc tiles.
// Q pre-scaled by 0.125*log2e; V also written transposed to vt[n-1024][m].
__global__ __launch_bounds__(512) void k_gemm(const u16* __restrict__ xb,
                                              const u16* __restrict__ wb,
                                              const float* __restrict__ bq,
                                              const float* __restrict__ bk,
                                              const float* __restrict__ bv,
                                              const float* __restrict__ bs,
                                              u16* __restrict__ qkvs,
                                              u16* __restrict__ vt) {
    __shared__ __align__(16) u16 A_lds[128 * 64];
    __shared__ __align__(16) u16 B_lds[128 * 64];
    int tid = threadIdx.x;
    int w = tid >> 6, lane = tid & 63;
    int wr = w >> 1, wc = w & 1;
    int L = lane & 15, q = lane >> 4;
    int m0 = blockIdx.y * 128, n0 = blockIdx.x * 128;

    const f4 fz = {0.f, 0.f, 0.f, 0.f};
    f4 acc[2][4];
#pragma unroll
    for (int r = 0; r < 2; r++)
#pragma unroll
        for (int t = 0; t < 4; t++) acc[r][t] = fz;

    int r8 = lane >> 3;                 // source row within 8-row group
    int csw = ((lane & 7) ^ r8) * 8;    // XOR-swizzled source chunk (u16 units)
    // staging: waves 0-3 stage A rows 32w.., waves 4-7 stage B rows 32(w-4)..
    const u16* gS;
    u16* lds_s;
    int rb0;
    if (w < 4) { gS = xb + (size_t)(m0 + r8) * 4096 + csw; lds_s = A_lds; rb0 = 32 * w; }
    else       { gS = wb + (size_t)(n0 + r8) * 4096 + csw; lds_s = B_lds; rb0 = 32 * (w - 4); }

    for (int kt = 0; kt < 64; ++kt) {
        int k0 = kt * 64;
#pragma unroll
        for (int g = 0; g < 4; g++) {
            int rb = rb0 + 8 * g;
            GLD16(gS + (size_t)rb * 4096 + k0, &lds_s[rb * 64]);
        }
        __syncthreads();
        s8v a[2][2], b[4][2];
#pragma unroll
        for (int r = 0; r < 2; r++) {
            int row = wr * 32 + 16 * r + L;
            int r7 = row & 7;
            a[r][0] = *(const s8v*)&A_lds[row * 64 + ((q ^ r7) * 8)];
            a[r][1] = *(const s8v*)&A_lds[row * 64 + (((4 + q) ^ r7) * 8)];
        }
#pragma unroll
        for (int t = 0; t < 4; t++) {
            int row = wc * 64 + 16 * t + L;
            int r7 = row & 7;
            b[t][0] = *(const s8v*)&B_lds[row * 64 + ((q ^ r7) * 8)];
            b[t][1] = *(const s8v*)&B_lds[row * 64 + (((4 + q) ^ r7) * 8)];
        }
#pragma unroll
        for (int r = 0; r < 2; r++)
#pragma unroll
            for (int t = 0; t < 4; t++) {
                acc[r][t] = __builtin_amdgcn_mfma_f32_16x16x32_bf16(a[r][0], b[t][0], acc[r][t], 0, 0, 0);
                acc[r][t] = __builtin_amdgcn_mfma_f32_16x16x32_bf16(a[r][1], b[t][1], acc[r][t], 0, 0, 0);
            }
        __syncthreads();
    }

#pragma unroll
    for (int t = 0; t < 4; t++) {
        int n = n0 + wc * 64 + 16 * t + L;
        int seg = n >> 9, o = n & 511;
        const float* bp = (seg == 0) ? bq : (seg == 1) ? bk : (seg == 2) ? bv : bs;
        float bias = bp[o];
        float scale = (seg == 0) ? 0.1803368801f : 1.f;  // 0.125 * log2(e)
#pragma unroll
        for (int r = 0; r < 2; r++) {
            int mbase = m0 + wr * 32 + 16 * r + 4 * q;
            u16x4 hv;
#pragma unroll
            for (int q2 = 0; q2 < 4; q2++) {
                u16 hb = f2bf((acc[r][t][q2] + bias) * scale);
                hv[q2] = hb;
                qkvs[(size_t)(mbase + q2) * 2048 + n] = hb;
            }
            if (seg == 2)  // fused V transpose: vt[d][m], 4 contiguous m -> 8B store
                *(u16x4*)&vt[(size_t)(n - 1024) * 4096 + mbase] = hv;
        }
    }
}

// ---------- split-j max-free attention ----------
// block = (i-tile 64, head h, split sp); 4 waves, wave w owns rows 16w..16w+15.
// K/V'/Q staged via GLD16 into unpadded 64x64 tiles with XOR chunk swizzle.
// Q pre-scaled by 0.125*log2e: p = exp2(min(qk' + xx*qe', 115)) -- no running max
// (scores bounded far below fp32 overflow); partials o, l, sa are pure sums.
__global__ __launch_bounds__(256, 4) void k_attn(const u16* __restrict__ qkvs,
                                                 const u16* __restrict__ xb,
                                                 const u16* __restrict__ vt,
                                                 const float* __restrict__ we,
                                                 float* __restrict__ o_part,
                                                 float* __restrict__ lsa_part) {
    __shared__ __align__(16) u16 K_lds[64 * 64];  // swizzled (also Q staging)
    __shared__ __align__(16) u16 V_lds[64 * 64];  // swizzled, rows=d cols=j
    __shared__ __align__(16) u16 P_lds[64 * 72];  // padded, plain layout
    __shared__ __align__(16) u16 X_lds[64 * 72];  // padded bf16 x tile [j][i]
    __shared__ float qe8[64];

    int tid = threadIdx.x;
    int w = tid >> 6, lane = tid & 63;
    int L = lane & 15, q = lane >> 4;
    int i0 = blockIdx.x * 64;
    int h = blockIdx.y, hc = h * 64;
    int sp = blockIdx.z;

    int r8 = lane >> 3;                 // GLD16 source row within 8-row group
    int csw = ((lane & 7) ^ r8) * 8;    // XOR-swizzled source chunk (u16 units)

    // ---- stage Q into K_lds (GLD16, swizzled) ----
    {
        const u16* g0 = qkvs + (size_t)i0 * 2048 + hc;
#pragma unroll
        for (int ih = 0; ih < 2; ih++) {
            int rb = 16 * w + 8 * ih;
            GLD16(g0 + (size_t)(rb + r8) * 2048 + csw, &K_lds[rb * 64]);
        }
    }
    __syncthreads();

    s8v qf[2];
#pragma unroll
    for (int c = 0; c < 2; c++) {
        int row = 16 * w + L;
        qf[c] = *(const s8v*)&K_lds[row * 64 + (((4 * c + q) ^ (row & 7)) * 8)];
    }
    if (tid < 64) {  // qe8[i] = q'_i . we_h   (q' already carries 0.125*log2e)
        float s = 0.f;
        int r7 = tid & 7;
#pragma unroll
        for (int d = 0; d < 64; d++)
            s += bf2f(K_lds[tid * 64 + ((d >> 3) ^ r7) * 8 + (d & 7)]) * we[hc + d];
        qe8[tid] = s;
    }
    __syncthreads();

    float qe_r[4];
#pragma unroll
    for (int r = 0; r < 4; r++) qe_r[r] = qe8[16 * w + 4 * q + r];

    const f4 fz = {0.f, 0.f, 0.f, 0.f};
    f4 o_acc[4];
    float l_p[4], sa_p[4];
#pragma unroll
    for (int r = 0; r < 4; r++) { l_p[r] = 0.f; sa_p[r] = 0.f; }
#pragma unroll
    for (int t = 0; t < 4; t++) o_acc[t] = fz;

    for (int jt64 = 0; jt64 < 32; ++jt64) {
        int j0 = sp * 2048 + jt64 * 64;
        // stage K (GLD16)
        {
            const u16* g0 = qkvs + (size_t)j0 * 2048 + 512 + hc;
#pragma unroll
            for (int ih = 0; ih < 2; ih++) {
                int rb = 16 * w + 8 * ih;
                GLD16(g0 + (size_t)(rb + r8) * 2048 + csw, &K_lds[rb * 64]);
            }
        }
        // stage V^T (GLD16): rows are d, cols j
        {
            const u16* g0 = vt + (size_t)hc * 4096 + j0;
#pragma unroll
            for (int ih = 0; ih < 2; ih++) {
                int rb = 16 * w + 8 * ih;
                GLD16(g0 + (size_t)(rb + r8) * 4096 + csw, &V_lds[rb * 64]);
            }
        }
        // stage X tile bf16: X_lds[j][i] (padded 72, plain)
#pragma unroll
        for (int qq = 0; qq < 2; qq++) {
            int idx = tid + 256 * qq;
            int row = idx >> 3, c8 = (idx & 7) * 8;
            *(s8v*)&X_lds[row * 72 + c8] =
                *(const s8v*)&xb[(size_t)(j0 + row) * 4096 + i0 + c8];
        }
        __syncthreads();

#pragma unroll
        for (int jt = 0; jt < 4; jt++) {
            int n = L + 16 * jt;
            int n7 = n & 7;
            s8v b0 = *(const s8v*)&K_lds[n * 64 + ((q ^ n7) * 8)];
            s8v b1 = *(const s8v*)&K_lds[n * 64 + (((4 + q) ^ n7) * 8)];
            f4 acc = fz;
            acc = __builtin_amdgcn_mfma_f32_16x16x32_bf16(qf[0], b0, acc, 0, 0, 0);
            acc = __builtin_amdgcn_mfma_f32_16x16x32_bf16(qf[1], b1, acc, 0, 0, 0);
            u16x4 xv4 = *(const u16x4*)&X_lds[n * 72 + 16 * w + 4 * q];
#pragma unroll
            for (int r = 0; r < 4; r++) {
                float xx = bf2f(xv4[r]);
                float s = fminf(acc[r] + xx * qe_r[r], 115.f);   // log2 units
                float p = __builtin_amdgcn_exp2f(s);
                l_p[r] += p;
                sa_p[r] += p * xx;
                P_lds[(16 * w + 4 * q + r) * 72 + n] = f2bf_hu(p);
            }
        }

        // PV (wave-local P round-trip; same-wave rows only)
        {
            int row = 16 * w + L;
            s8v a0 = *(const s8v*)&P_lds[row * 72 + q * 8];
            s8v a1 = *(const s8v*)&P_lds[row * 72 + 32 + q * 8];
#pragma unroll
            for (int t = 0; t < 4; t++) {
                int n = L + 16 * t;
                int n7 = n & 7;
                s8v b0 = *(const s8v*)&V_lds[n * 64 + ((q ^ n7) * 8)];
                s8v b1 = *(const s8v*)&V_lds[n * 64 + (((4 + q) ^ n7) * 8)];
                o_acc[t] = __builtin_amdgcn_mfma_f32_16x16x32_bf16(a0, b0, o_acc[t], 0, 0, 0);
                o_acc[t] = __builtin_amdgcn_mfma_f32_16x16x32_bf16(a1, b1, o_acc[t], 0, 0, 0);
            }
        }
        __syncthreads();
    }

    // epilogue: write raw partials (division happens in k_comb after summing l)
#pragma unroll
    for (int r = 0; r < 4; r++) {
        float l = l_p[r], sa = sa_p[r];
        l += __shfl_xor(l, 1);  sa += __shfl_xor(sa, 1);
        l += __shfl_xor(l, 2);  sa += __shfl_xor(sa, 2);
        l += __shfl_xor(l, 4);  sa += __shfl_xor(sa, 4);
        l += __shfl_xor(l, 8);  sa += __shfl_xor(sa, 8);
        int i = i0 + 16 * w + 4 * q + r;
#pragma unroll
        for (int t = 0; t < 4; t++)
            o_part[((size_t)sp * 4096 + i) * 512 + hc + L + 16 * t] = o_acc[t][r];
        if (L == 0) {
            size_t bi = (((size_t)sp * 4096 + i) * 8 + h) * 2;
            lsa_part[bi] = l;
            lsa_part[bi + 1] = sa;
        }
    }
}

// ---------- combine splits + skip + out_pre + column stats ----------
__global__ __launch_bounds__(512) void k_comb(const float* __restrict__ o_part,
                                              const float* __restrict__ lsa,
                                              const u16* __restrict__ qkvs,
                                              const float* __restrict__ we,
                                              float* __restrict__ out_pre,
                                              float* __restrict__ stats) {
    int c = threadIdx.x;
    int r0 = blockIdx.x * 64;
    int h = c >> 6;
    float wec = we[c];
    float s = 0.f, s2 = 0.f;
    for (int ii = 0; ii < 64; ii++) {
        int i = r0 + ii;
        size_t b0 = ((size_t)i * 8 + h) * 2;
        size_t b1 = (((size_t)4096 + i) * 8 + h) * 2;
        float l = lsa[b0] + lsa[b1];
        float sa = lsa[b0 + 1] + lsa[b1 + 1];
        float o = o_part[(size_t)i * 512 + c] + o_part[((size_t)4096 + i) * 512 + c];
        float inv = 1.f / l;
        float v = (o + sa * wec) * inv + bf2f(qkvs[(size_t)i * 2048 + 1536 + c]);
        out_pre[(size_t)i * 512 + c] = v;
        s += v; s2 += v * v;
    }
    atomicAdd(&stats[c], s);
    atomicAdd(&stats[512 + c], s2);
}

// ---------- GraphNorm + per-row L2 normalize ----------
__global__ __launch_bounds__(512) void k_final(const float* __restrict__ out_pre,
                                               const float* __restrict__ stats,
                                               const float* __restrict__ gn_w,
                                               const float* __restrict__ gn_b,
                                               const float* __restrict__ gn_ms,
                                               float* __restrict__ out) {
    __shared__ float red[8];
    int c = threadIdx.x;
    int i = blockIdx.x;
    float mean = stats[c] * (1.f / 4096.f);
    float ex2 = stats[512 + c] * (1.f / 4096.f);
    float g = gn_ms[c];
    float var = ex2 - (2.f * g - g * g) * mean * mean;
    float y = gn_w[c] * (out_pre[(size_t)i * 512 + c] - g * mean) * rsqrtf(var + 1e-5f) + gn_b[c];
    float qv = y * y;
    qv += __shfl_xor(qv, 1);  qv += __shfl_xor(qv, 2);  qv += __shfl_xor(qv, 4);
    qv += __shfl_xor(qv, 8);  qv += __shfl_xor(qv, 16); qv += __shfl_xor(qv, 32);
    if ((c & 63) == 0) red[c >> 6] = qv;
    __syncthreads();
    float tot = 0.f;
#pragma unroll
    for (int k = 0; k < 8; k++) tot += red[k];
    out[(size_t)i * 512 + c] = y * rsqrtf(tot);
}

extern "C" void kernel_launch(void* const* d_in, const int* in_sizes, int n_in,
                              void* d_out, int out_size, void* d_ws, size_t ws_size,
                              hipStream_t stream) {
    (void)in_sizes; (void)n_in; (void)out_size; (void)ws_size;
    const float* x    = (const float*)d_in[0];
    const float* Wq   = (const float*)d_in[1];
    const float* bq   = (const float*)d_in[2];
    const float* Wk   = (const float*)d_in[3];
    const float* bk   = (const float*)d_in[4];
    const float* Wv   = (const float*)d_in[5];
    const float* bv   = (const float*)d_in[6];
    const float* we   = (const float*)d_in[7];
    const float* Ws   = (const float*)d_in[8];
    const float* bs   = (const float*)d_in[9];
    const float* gnw  = (const float*)d_in[10];
    const float* gnb  = (const float*)d_in[11];
    const float* gnms = (const float*)d_in[12];
    float* out = (float*)d_out;

    char* ws = (char*)d_ws;
    // Region reuse (all launches sequential on `stream`):
    //   [0,32M):   xb (convx..attn) then out_pre overlays (comb..final)
    //   [32M,48M): wb (transw..gemm) then o_part overlays (attn..comb)
    //   [48M,64M): qkvs (gemm..comb)
    //   [64M,68M): vt (gemm..attn)
    //   [68M,+512K): lsa_part ; stats after it
    u16* xb        = (u16*)(ws);
    float* out_pre = (float*)(ws);
    u16* wb        = (u16*)(ws + (size_t)33554432);
    float* o_part  = (float*)(ws + (size_t)33554432);
    u16* qkvs      = (u16*)(ws + (size_t)50331648);
    u16* vt        = (u16*)(ws + (size_t)67108864);
    float* lsa     = (float*)(ws + (size_t)71303168);
    float* stats   = (float*)(ws + (size_t)71303168 + 524288);

    k_convx<<<8192, 256, 0, stream>>>(x, xb, stats);
    k_transw<<<dim3(64, 32), 256, 0, stream>>>(Wq, Wk, Wv, Ws, wb);
    k_gemm<<<dim3(16, 32), 512, 0, stream>>>(xb, wb, bq, bk, bv, bs, qkvs, vt);
    k_attn<<<dim3(64, 8, 2), 256, 0, stream>>>(qkvs, xb, vt, we, o_part, lsa);
    k_comb<<<64, 512, 0, stream>>>(o_part, lsa, qkvs, we, out_pre, stats);
    k_final<<<4096, 512, 0, stream>>>(out_pre, stats, gnw, gnb, gnms, out);
}